// Round 2
// baseline (2701.628 us; speedup 1.0000x reference)
//
#include <hip/hip_runtime.h>
#include <cstdint>

#define B_   32
#define CIN  3
#define HW_  512
#define C_   512
#define CQK  64
#define PSZ  16
#define NP   1024      // patches per image (32x32)
#define TP   16        // patches (n's) per block
#define NBLK (B_ * NP / TP)   // 2048

// ---------------------------------------------------------------------------
// Kernel 1: fused patchify-conv (3->512, k16 s16) + q/k/v channel projections
// grid: 2048 blocks (b, n-tile of 16 patches), 256 threads
// ---------------------------------------------------------------------------
__global__ __launch_bounds__(256) void fused_patch_proj(
    const float* __restrict__ x,    // [B,3,512,512]
    const float* __restrict__ w1,   // [512,3,16,16] == [512][768]
    const float* __restrict__ wq, const float* __restrict__ bq,
    const float* __restrict__ wk, const float* __restrict__ bk,
    const float* __restrict__ wv, const float* __restrict__ bv,
    float* __restrict__ qws,        // [B][64][1024]  (transposed)
    float* __restrict__ kws,        // [B][64][1024]
    float* __restrict__ vws)        // [B][512][1024]
{
    __shared__ float patch[TP * 768];   // 48 KB  [tp][ci*256+ky*16+kx]
    __shared__ float xtile[TP * C_];    // 32 KB  [tp][c]

    const int tid = threadIdx.x;
    const int b   = blockIdx.x >> 6;         // /64 tiles per image
    const int n0  = (blockIdx.x & 63) * TP;  // first patch index in tile
    const int ph  = n0 >> 5;                 // patch row (same for all 16)
    const int pw0 = n0 & 31;                 // first patch col (0 or 16)

    // ---- load 16 patches (12288 floats = 3072 float4), coalesced ----
    {
        const float* xb = x + (size_t)b * CIN * HW_ * HW_;
        for (int idx4 = tid; idx4 < 3072; idx4 += 256) {
            int row  = idx4 >> 6;     // 0..47 = ci*16+ky
            int col4 = idx4 & 63;     // float4 within 256-float run
            int ci = row >> 4;
            int ky = row & 15;
            const float* src = xb + ((size_t)ci * HW_ + ph * PSZ + ky) * HW_
                                  + pw0 * PSZ + col4 * 4;
            float4 vdat = *(const float4*)src;
            int col = col4 * 4;       // = tp*16 + kx
            int tp  = col >> 4;
            int kx  = col & 15;
            *(float4*)&patch[tp * 768 + ci * 256 + ky * 16 + kx] = vdat;
        }
    }
    __syncthreads();

    // ---- conv: each thread computes 2 output channels x 16 patches ----
    for (int cc = 0; cc < 2; ++cc) {
        int c = tid + cc * 256;
        const float4* wrow = (const float4*)(w1 + (size_t)c * 768);
        float acc[TP];
        #pragma unroll
        for (int tp = 0; tp < TP; ++tp) acc[tp] = 0.f;
        for (int j4 = 0; j4 < 192; ++j4) {
            float4 w4 = wrow[j4];
            #pragma unroll
            for (int tp = 0; tp < TP; ++tp) {
                float4 pv = *(const float4*)&patch[tp * 768 + j4 * 4];  // broadcast
                acc[tp] += w4.x * pv.x + w4.y * pv.y + w4.z * pv.z + w4.w * pv.w;
            }
        }
        #pragma unroll
        for (int tp = 0; tp < TP; ++tp) xtile[tp * C_ + c] = acc[tp];
    }
    __syncthreads();

    // ---- projections: 640 output rows (64 q + 64 k + 512 v) ----
    for (int o = tid; o < 640; o += 256) {
        const float* wrow; float bias; float* dst;
        if (o < CQK) {
            wrow = wq + (size_t)o * C_; bias = bq[o];
            dst = qws + ((size_t)b * CQK + o) * NP + n0;
        } else if (o < 2 * CQK) {
            int p = o - CQK;
            wrow = wk + (size_t)p * C_; bias = bk[p];
            dst = kws + ((size_t)b * CQK + p) * NP + n0;
        } else {
            int p = o - 2 * CQK;
            wrow = wv + (size_t)p * C_; bias = bv[p];
            dst = vws + ((size_t)b * C_ + p) * NP + n0;
        }
        float acc[TP];
        #pragma unroll
        for (int tp = 0; tp < TP; ++tp) acc[tp] = 0.f;
        const float4* w4p = (const float4*)wrow;
        for (int j4 = 0; j4 < 128; ++j4) {
            float4 w4 = w4p[j4];
            #pragma unroll
            for (int tp = 0; tp < TP; ++tp) {
                float4 xv = *(const float4*)&xtile[tp * C_ + j4 * 4];   // broadcast
                acc[tp] += w4.x * xv.x + w4.y * xv.y + w4.z * xv.z + w4.w * xv.w;
            }
        }
        #pragma unroll
        for (int tp = 0; tp < TP; ++tp) dst[tp] = acc[tp] + bias;
    }
}

// ---------------------------------------------------------------------------
// Kernel 2: fused energy (q.k, clip) + softmax + PV
// grid: 2048 blocks (b, 16 query rows), 256 threads
// out[b,c,n] = sum_m exp(clip(q_n . k_m)) * v[c,m] / denom_n
// ---------------------------------------------------------------------------
__global__ __launch_bounds__(256) void attn_kernel(
    const float* __restrict__ qws,  // [B][64][1024]
    const float* __restrict__ kws,  // [B][64][1024]
    const float* __restrict__ vws,  // [B][512][1024]
    float* __restrict__ out)        // [B][512][1024]
{
    __shared__ float qs[TP * CQK];   // 4 KB   [tn][j]
    __shared__ float es[TP * NP];    // 64 KB  [tn][m]
    __shared__ float dpart[4 * TP];  // per-wave denom partials

    const int tid = threadIdx.x;
    const int b   = blockIdx.x >> 6;
    const int n0  = (blockIdx.x & 63) * TP;

    // load q tile: qs[tn][j] = q[b][j][n0+tn]
    for (int idx = tid; idx < TP * CQK; idx += 256) {
        int j  = idx >> 4;
        int tn = idx & 15;
        qs[tn * CQK + j] = qws[((size_t)b * CQK + j) * NP + n0 + tn];
    }
    __syncthreads();

    // ---- phase 1: energies + exp, per-thread denom partials ----
    float psum[TP];
    #pragma unroll
    for (int t = 0; t < TP; ++t) psum[t] = 0.f;

    for (int m = tid; m < NP; m += 256) {
        float dot[TP];
        #pragma unroll
        for (int t = 0; t < TP; ++t) dot[t] = 0.f;
        #pragma unroll 4
        for (int j = 0; j < CQK; ++j) {
            float kv = kws[((size_t)b * CQK + j) * NP + m];   // coalesced
            #pragma unroll
            for (int t = 0; t < TP; ++t) dot[t] += kv * qs[t * CQK + j];
        }
        #pragma unroll
        for (int t = 0; t < TP; ++t) {
            float e = __expf(fminf(fmaxf(dot[t], -1.f), 1.f));
            es[t * NP + m] = e;
            psum[t] += e;
        }
    }

    // ---- denom: wave shfl reduce, deterministic 4-partial combine ----
    #pragma unroll
    for (int t = 0; t < TP; ++t) {
        float s = psum[t];
        s += __shfl_xor(s, 32);
        s += __shfl_xor(s, 16);
        s += __shfl_xor(s, 8);
        s += __shfl_xor(s, 4);
        s += __shfl_xor(s, 2);
        s += __shfl_xor(s, 1);
        psum[t] = s;
    }
    if ((tid & 63) == 0) {
        int w = tid >> 6;
        #pragma unroll
        for (int t = 0; t < TP; ++t) dpart[w * TP + t] = psum[t];
    }
    __syncthreads();

    // ---- phase 2: PV — each thread owns 2 channels, 16 n's ----
    const int c0 = tid;
    float acc0[TP], acc1[TP];
    #pragma unroll
    for (int t = 0; t < TP; ++t) { acc0[t] = 0.f; acc1[t] = 0.f; }

    const float4* v0 = (const float4*)(vws + ((size_t)b * C_ + c0) * NP);
    const float4* v1 = (const float4*)(vws + ((size_t)b * C_ + c0 + 256) * NP);
    const float4* e4 = (const float4*)es;

    for (int m4 = 0; m4 < NP / 4; ++m4) {
        float4 a  = v0[m4];
        float4 bb = v1[m4];
        #pragma unroll
        for (int t = 0; t < TP; ++t) {
            float4 ee = e4[t * (NP / 4) + m4];    // broadcast
            acc0[t] += ee.x * a.x  + ee.y * a.y  + ee.z * a.z  + ee.w * a.w;
            acc1[t] += ee.x * bb.x + ee.y * bb.y + ee.z * bb.z + ee.w * bb.w;
        }
    }

    float* ob = out + (size_t)b * C_ * NP;
    #pragma unroll
    for (int t = 0; t < TP; ++t) {
        float di = 1.0f / (dpart[0 * TP + t] + dpart[1 * TP + t] +
                           dpart[2 * TP + t] + dpart[3 * TP + t]);
        ob[(size_t)c0 * NP + n0 + t]        = acc0[t] * di;
        ob[(size_t)(c0 + 256) * NP + n0 + t] = acc1[t] * di;
    }
}

// ---------------------------------------------------------------------------
extern "C" void kernel_launch(void* const* d_in, const int* in_sizes, int n_in,
                              void* d_out, int out_size, void* d_ws, size_t ws_size,
                              hipStream_t stream) {
    const float* x  = (const float*)d_in[0];
    const float* w1 = (const float*)d_in[1];
    const float* wq = (const float*)d_in[2];
    const float* bq = (const float*)d_in[3];
    const float* wk = (const float*)d_in[4];
    const float* bk = (const float*)d_in[5];
    const float* wv = (const float*)d_in[6];
    const float* bv = (const float*)d_in[7];
    float* out = (float*)d_out;

    float* qws = (float*)d_ws;                              // 8 MB
    float* kws = qws + (size_t)B_ * CQK * NP;               // 8 MB
    float* vws = kws + (size_t)B_ * CQK * NP;               // 64 MB
    // total ws use: 80 MB

    fused_patch_proj<<<NBLK, 256, 0, stream>>>(x, w1, wq, bq, wk, bk, wv, bv,
                                               qws, kws, vws);
    attn_kernel<<<NBLK, 256, 0, stream>>>(qws, kws, vws, out);
}

// Round 3
// 482.732 us; speedup vs baseline: 5.5965x; 5.5965x over previous
//
#include <hip/hip_runtime.h>
#include <cstdint>

typedef unsigned short u16;
typedef unsigned int u32;
typedef __attribute__((ext_vector_type(8))) short bf16x8;
typedef __attribute__((ext_vector_type(4))) float f32x4;

#define B_   32
#define C_   512
#define CQK  64
#define NP   1024

// byte offset into a [rows][64 bf16] LDS tile (row stride 128 B, 16B-slot XOR swizzle)
#define LOFF(row, kb) (((row) << 7) + ((kb) ^ (((row) & 7) << 4)))

__device__ __forceinline__ u16 f2bf(float f) {
    u32 u = __float_as_uint(f);
    u += 0x7FFF + ((u >> 16) & 1);
    return (u16)(u >> 16);
}
__device__ __forceinline__ float bfres(float f, u16 h) {   // f - float(hi)
    return f - __uint_as_float(((u32)h) << 16);
}

// write 16 bf16 values into tile at (row, kb..kb+31 bytes) honoring swizzle
__device__ __forceinline__ void put16(u16* tile, int row, int kb, const u16* v) {
    char* p = (char*)tile;
    *(ushort4*)(p + LOFF(row, kb))          = *(const ushort4*)(v + 0);
    *(ushort4*)(p + LOFF(row, kb) + 8)      = *(const ushort4*)(v + 4);
    *(ushort4*)(p + LOFF(row, kb + 16))     = *(const ushort4*)(v + 8);
    *(ushort4*)(p + LOFF(row, kb + 16) + 8) = *(const ushort4*)(v + 12);
}

// load 16 fp32, produce hi/lo bf16 splits
__device__ __forceinline__ void split16(const float* src, u16* h, u16* l) {
    float f[16];
    *(float4*)&f[0]  = *(const float4*)(src + 0);
    *(float4*)&f[4]  = *(const float4*)(src + 4);
    *(float4*)&f[8]  = *(const float4*)(src + 8);
    *(float4*)&f[12] = *(const float4*)(src + 12);
    #pragma unroll
    for (int i = 0; i < 16; ++i) {
        h[i] = f2bf(f[i]);
        l[i] = f2bf(bfres(f[i], h[i]));
    }
}
__device__ __forceinline__ void cvt16(const float* src, u16* h) {
    float f[16];
    *(float4*)&f[0]  = *(const float4*)(src + 0);
    *(float4*)&f[4]  = *(const float4*)(src + 4);
    *(float4*)&f[8]  = *(const float4*)(src + 8);
    *(float4*)&f[12] = *(const float4*)(src + 12);
    #pragma unroll
    for (int i = 0; i < 16; ++i) h[i] = f2bf(f[i]);
}

#define MFMA(a, b, c) __builtin_amdgcn_mfma_f32_16x16x32_bf16((a), (b), (c), 0, 0, 0)

// ---------------------------------------------------------------------------
// Kernel A: patchify conv as GEMM, split-bf16.  D[cout, n] = W1[cout, k] * Patch[k, n]
// tile 128m x 64n, BK=64, K=768 (12 steps).  grid (512, 4)
// outputs xhi/xlo [b][n][c]
// ---------------------------------------------------------------------------
__global__ __launch_bounds__(256) void convA(
    const float* __restrict__ x, const float* __restrict__ w1,
    u16* __restrict__ xhi, u16* __restrict__ xlo)
{
    __shared__ u16 Ah[128 * 64], Al[128 * 64], Bh[64 * 64], Bl[64 * 64];
    const int tid = threadIdx.x;
    const int b = blockIdx.x >> 4, nt = blockIdx.x & 15;
    const int n0 = nt * 64, ph0 = nt * 2;
    const int m0 = blockIdx.y * 128;
    const int wid = tid >> 6, lane = tid & 63;
    const int wm = wid >> 1, wn = wid & 1;
    const int lr = lane & 15, lk = lane >> 4;

    f32x4 acc[4][2];
    #pragma unroll
    for (int i = 0; i < 4; ++i) {
        acc[i][0] = f32x4{0.f, 0.f, 0.f, 0.f};
        acc[i][1] = f32x4{0.f, 0.f, 0.f, 0.f};
    }

    for (int s = 0; s < 12; ++s) {
        const int k0 = s * 64;
        const int ci = s >> 2, ky0 = (s & 3) * 4;
        __syncthreads();
        // --- stage A (w1 fp32 -> hi/lo) : 128 rows x 64 k
        #pragma unroll
        for (int it = 0; it < 2; ++it) {
            int idx = tid + it * 256;
            int row = idx >> 2, q = idx & 3;
            u16 h[16], l[16];
            split16(w1 + (size_t)(m0 + row) * 768 + k0 + q * 16, h, l);
            put16(Ah, row, q * 32, h);
            put16(Al, row, q * 32, l);
        }
        // --- stage B (im2col gather, fp32 -> hi/lo) : 64 n x 64 k
        {
            int r = tid >> 5, phl = r >> 2, kyl = r & 3;
            int f0 = (tid & 31) * 16;
            int y = (ph0 + phl) * 16 + ky0 + kyl;
            const float* src = x + (((size_t)b * 3 + ci) * 512 + y) * 512 + f0;
            int n = phl * 32 + (f0 >> 4);
            u16 h[16], l[16];
            split16(src, h, l);
            put16(Bh, n, kyl * 32, h);
            put16(Bl, n, kyl * 32, l);
        }
        __syncthreads();
        #pragma unroll
        for (int kk = 0; kk < 2; ++kk) {
            const int kb = kk * 64 + lk * 16;
            bf16x8 ah[4], al[4], bh[2], bl[2];
            #pragma unroll
            for (int mi = 0; mi < 4; ++mi) {
                int row = wm * 64 + mi * 16 + lr;
                ah[mi] = *(const bf16x8*)((const char*)Ah + LOFF(row, kb));
                al[mi] = *(const bf16x8*)((const char*)Al + LOFF(row, kb));
            }
            #pragma unroll
            for (int ni = 0; ni < 2; ++ni) {
                int row = wn * 32 + ni * 16 + lr;
                bh[ni] = *(const bf16x8*)((const char*)Bh + LOFF(row, kb));
                bl[ni] = *(const bf16x8*)((const char*)Bl + LOFF(row, kb));
            }
            #pragma unroll
            for (int mi = 0; mi < 4; ++mi)
            #pragma unroll
            for (int ni = 0; ni < 2; ++ni) {
                acc[mi][ni] = MFMA(ah[mi], bh[ni], acc[mi][ni]);
                acc[mi][ni] = MFMA(ah[mi], bl[ni], acc[mi][ni]);
                acc[mi][ni] = MFMA(al[mi], bh[ni], acc[mi][ni]);
            }
        }
    }
    // epilogue: split + transposed-ish store to xhi/xlo[b][n][c]
    #pragma unroll
    for (int mi = 0; mi < 4; ++mi)
    #pragma unroll
    for (int ni = 0; ni < 2; ++ni) {
        int c0 = m0 + wm * 64 + mi * 16 + lk * 4;
        int n  = n0 + wn * 32 + ni * 16 + lr;
        ushort4 h4, l4;
        float v0 = acc[mi][ni][0], v1 = acc[mi][ni][1];
        float v2 = acc[mi][ni][2], v3 = acc[mi][ni][3];
        h4.x = f2bf(v0); l4.x = f2bf(bfres(v0, h4.x));
        h4.y = f2bf(v1); l4.y = f2bf(bfres(v1, h4.y));
        h4.z = f2bf(v2); l4.z = f2bf(bfres(v2, h4.z));
        h4.w = f2bf(v3); l4.w = f2bf(bfres(v3, h4.w));
        size_t base = ((size_t)b * NP + n) * C_ + c0;
        *(ushort4*)&xhi[base] = h4;
        *(ushort4*)&xlo[base] = l4;
    }
}

// ---------------------------------------------------------------------------
// Kernel P1: q/k projection, split-bf16.  rows 0..63 = q, 64..127 = k.
// tile 128m x 64n, K=512 (8 steps).  grid 512.  outputs q/k hi,lo [b][n][64]
// ---------------------------------------------------------------------------
__global__ __launch_bounds__(256) void projQK(
    const u16* __restrict__ xhi, const u16* __restrict__ xlo,
    const float* __restrict__ wq, const float* __restrict__ bq,
    const float* __restrict__ wk, const float* __restrict__ bk,
    u16* __restrict__ qhi, u16* __restrict__ qlo,
    u16* __restrict__ khi, u16* __restrict__ klo)
{
    __shared__ u16 Wh[128 * 64], Wl[128 * 64], Xh[64 * 64], Xl[64 * 64];
    __shared__ float biasS[128];
    const int tid = threadIdx.x;
    const int b = blockIdx.x >> 4, n0 = (blockIdx.x & 15) * 64;
    const int wid = tid >> 6, lane = tid & 63;
    const int wm = wid >> 1, wn = wid & 1;
    const int lr = lane & 15, lk = lane >> 4;
    if (tid < 128) biasS[tid] = (tid < 64) ? bq[tid] : bk[tid - 64];

    f32x4 acc[4][2];
    #pragma unroll
    for (int i = 0; i < 4; ++i) {
        acc[i][0] = f32x4{0.f, 0.f, 0.f, 0.f};
        acc[i][1] = f32x4{0.f, 0.f, 0.f, 0.f};
    }

    for (int s = 0; s < 8; ++s) {
        const int k0 = s * 64;
        __syncthreads();
        #pragma unroll
        for (int it = 0; it < 2; ++it) {
            int idx = tid + it * 256;
            int row = idx >> 2, q = idx & 3;
            const float* src = (row < 64 ? wq + (size_t)row * C_
                                         : wk + (size_t)(row - 64) * C_) + k0 + q * 16;
            u16 h[16], l[16];
            split16(src, h, l);
            put16(Wh, row, q * 32, h);
            put16(Wl, row, q * 32, l);
        }
        #pragma unroll
        for (int it = 0; it < 4; ++it) {
            int idx = tid + it * 256;
            int sel = idx >> 9, u = idx & 511;
            int row = u >> 3, ch = u & 7;
            const u16* src = (sel ? xlo : xhi) + ((size_t)b * NP + n0 + row) * C_ + k0 + ch * 8;
            uint4 v = *(const uint4*)src;
            *(uint4*)((char*)(sel ? Xl : Xh) + LOFF(row, ch * 16)) = v;
        }
        __syncthreads();
        #pragma unroll
        for (int kk = 0; kk < 2; ++kk) {
            const int kb = kk * 64 + lk * 16;
            bf16x8 ah[4], al[4], bh[2], bl[2];
            #pragma unroll
            for (int mi = 0; mi < 4; ++mi) {
                int row = wm * 64 + mi * 16 + lr;
                ah[mi] = *(const bf16x8*)((const char*)Wh + LOFF(row, kb));
                al[mi] = *(const bf16x8*)((const char*)Wl + LOFF(row, kb));
            }
            #pragma unroll
            for (int ni = 0; ni < 2; ++ni) {
                int row = wn * 32 + ni * 16 + lr;
                bh[ni] = *(const bf16x8*)((const char*)Xh + LOFF(row, kb));
                bl[ni] = *(const bf16x8*)((const char*)Xl + LOFF(row, kb));
            }
            #pragma unroll
            for (int mi = 0; mi < 4; ++mi)
            #pragma unroll
            for (int ni = 0; ni < 2; ++ni) {
                acc[mi][ni] = MFMA(ah[mi], bh[ni], acc[mi][ni]);
                acc[mi][ni] = MFMA(ah[mi], bl[ni], acc[mi][ni]);
                acc[mi][ni] = MFMA(al[mi], bh[ni], acc[mi][ni]);
            }
        }
    }
    #pragma unroll
    for (int mi = 0; mi < 4; ++mi)
    #pragma unroll
    for (int ni = 0; ni < 2; ++ni) {
        int j0 = wm * 64 + mi * 16 + lk * 4;
        int n  = n0 + wn * 32 + ni * 16 + lr;
        float4 bb = *(float4*)&biasS[j0];
        float v0 = acc[mi][ni][0] + bb.x, v1 = acc[mi][ni][1] + bb.y;
        float v2 = acc[mi][ni][2] + bb.z, v3 = acc[mi][ni][3] + bb.w;
        ushort4 h4, l4;
        h4.x = f2bf(v0); l4.x = f2bf(bfres(v0, h4.x));
        h4.y = f2bf(v1); l4.y = f2bf(bfres(v1, h4.y));
        h4.z = f2bf(v2); l4.z = f2bf(bfres(v2, h4.z));
        h4.w = f2bf(v3); l4.w = f2bf(bfres(v3, h4.w));
        if (wm == 0) {
            size_t base = ((size_t)b * NP + n) * CQK + j0;
            *(ushort4*)&qhi[base] = h4;
            *(ushort4*)&qlo[base] = l4;
        } else {
            size_t base = ((size_t)b * NP + n) * CQK + (j0 - 64);
            *(ushort4*)&khi[base] = h4;
            *(ushort4*)&klo[base] = l4;
        }
    }
}

// ---------------------------------------------------------------------------
// Kernel P2: v projection, single bf16.  D[n, cout] = x[n, c] * Wv^T[c, cout]
// tile 128n x 64cout, K=512 (8 steps).  grid (256, 8).  output v [b][cout][n]
// ---------------------------------------------------------------------------
__global__ __launch_bounds__(256) void projV(
    const u16* __restrict__ xhi, const float* __restrict__ wv,
    const float* __restrict__ bv, u16* __restrict__ vws)
{
    __shared__ u16 Xt[128 * 64], Wt[64 * 64];
    __shared__ float biasS[64];
    const int tid = threadIdx.x;
    const int b = blockIdx.x >> 3, n0 = (blockIdx.x & 7) * 128;
    const int c0 = blockIdx.y * 64;
    const int wid = tid >> 6, lane = tid & 63;
    const int wm = wid >> 1, wn = wid & 1;
    const int lr = lane & 15, lk = lane >> 4;
    if (tid < 64) biasS[tid] = bv[c0 + tid];

    f32x4 acc[4][2];
    #pragma unroll
    for (int i = 0; i < 4; ++i) {
        acc[i][0] = f32x4{0.f, 0.f, 0.f, 0.f};
        acc[i][1] = f32x4{0.f, 0.f, 0.f, 0.f};
    }

    for (int s = 0; s < 8; ++s) {
        const int k0 = s * 64;
        __syncthreads();
        #pragma unroll
        for (int it = 0; it < 4; ++it) {
            int idx = tid + it * 256;
            int row = idx >> 3, ch = idx & 7;
            const u16* src = xhi + ((size_t)b * NP + n0 + row) * C_ + k0 + ch * 8;
            uint4 v = *(const uint4*)src;
            *(uint4*)((char*)Xt + LOFF(row, ch * 16)) = v;
        }
        {
            int row = tid >> 2, q = tid & 3;
            u16 h[16];
            cvt16(wv + (size_t)(c0 + row) * C_ + k0 + q * 16, h);
            put16(Wt, row, q * 32, h);
        }
        __syncthreads();
        #pragma unroll
        for (int kk = 0; kk < 2; ++kk) {
            const int kb = kk * 64 + lk * 16;
            bf16x8 a[4], bfr[2];
            #pragma unroll
            for (int mi = 0; mi < 4; ++mi) {
                int row = wm * 64 + mi * 16 + lr;
                a[mi] = *(const bf16x8*)((const char*)Xt + LOFF(row, kb));
            }
            #pragma unroll
            for (int ni = 0; ni < 2; ++ni) {
                int row = wn * 32 + ni * 16 + lr;
                bfr[ni] = *(const bf16x8*)((const char*)Wt + LOFF(row, kb));
            }
            #pragma unroll
            for (int mi = 0; mi < 4; ++mi)
            #pragma unroll
            for (int ni = 0; ni < 2; ++ni)
                acc[mi][ni] = MFMA(a[mi], bfr[ni], acc[mi][ni]);
        }
    }
    #pragma unroll
    for (int mi = 0; mi < 4; ++mi)
    #pragma unroll
    for (int ni = 0; ni < 2; ++ni) {
        int nr0 = n0 + wm * 64 + mi * 16 + lk * 4;
        int c   = c0 + wn * 32 + ni * 16 + lr;
        float bias = biasS[wn * 32 + ni * 16 + lr];
        ushort4 h4;
        h4.x = f2bf(acc[mi][ni][0] + bias);
        h4.y = f2bf(acc[mi][ni][1] + bias);
        h4.z = f2bf(acc[mi][ni][2] + bias);
        h4.w = f2bf(acc[mi][ni][3] + bias);
        *(ushort4*)&vws[((size_t)b * C_ + c) * NP + nr0] = h4;
    }
}

// ---------------------------------------------------------------------------
// Kernel B: E^T[m,n] = k_m . q_n  (split-bf16, swapped operands), clip, exp,
// running Z[n]; writes unnormalized P[b][n][m] bf16 + Z[b][n] fp32.
// block: (b, 64 n).  m-loop 16 x 64.  grid 512.
// ---------------------------------------------------------------------------
__global__ __launch_bounds__(256) void attnE(
    const u16* __restrict__ qhi, const u16* __restrict__ qlo,
    const u16* __restrict__ khi, const u16* __restrict__ klo,
    u16* __restrict__ Pws, float* __restrict__ Zws)
{
    __shared__ u16 Kh[64 * 64], Kl[64 * 64], Qh[64 * 64], Ql[64 * 64];
    __shared__ float zs[64];
    const int tid = threadIdx.x;
    const int b = blockIdx.x >> 4, n0 = (blockIdx.x & 15) * 64;
    const int wid = tid >> 6, lane = tid & 63;
    const int wr = wid >> 1, wn = wid & 1;
    const int lr = lane & 15, lk = lane >> 4;
    if (tid < 64) zs[tid] = 0.f;

    // stage Q (hi+lo) once
    #pragma unroll
    for (int it = 0; it < 4; ++it) {
        int idx = tid + it * 256;
        int sel = idx >> 9, u = idx & 511;
        int row = u >> 3, ch = u & 7;
        const u16* src = (sel ? qlo : qhi) + ((size_t)b * NP + n0 + row) * CQK + ch * 8;
        uint4 v = *(const uint4*)src;
        *(uint4*)((char*)(sel ? Ql : Qh) + LOFF(row, ch * 16)) = v;
    }
    __syncthreads();
    // hoist Q frags to registers
    bf16x8 qh[2][2], ql[2][2];
    #pragma unroll
    for (int ni = 0; ni < 2; ++ni)
    #pragma unroll
    for (int kk = 0; kk < 2; ++kk) {
        int row = wn * 32 + ni * 16 + lr;
        int kb = kk * 64 + lk * 16;
        qh[ni][kk] = *(const bf16x8*)((const char*)Qh + LOFF(row, kb));
        ql[ni][kk] = *(const bf16x8*)((const char*)Ql + LOFF(row, kb));
    }

    float z[2] = {0.f, 0.f};
    for (int ms = 0; ms < 16; ++ms) {
        const int m0 = ms * 64;
        __syncthreads();
        #pragma unroll
        for (int it = 0; it < 4; ++it) {
            int idx = tid + it * 256;
            int sel = idx >> 9, u = idx & 511;
            int row = u >> 3, ch = u & 7;
            const u16* src = (sel ? klo : khi) + ((size_t)b * NP + m0 + row) * CQK + ch * 8;
            uint4 v = *(const uint4*)src;
            *(uint4*)((char*)(sel ? Kl : Kh) + LOFF(row, ch * 16)) = v;
        }
        __syncthreads();
        f32x4 e[2][2];
        #pragma unroll
        for (int i = 0; i < 2; ++i) {
            e[i][0] = f32x4{0.f, 0.f, 0.f, 0.f};
            e[i][1] = f32x4{0.f, 0.f, 0.f, 0.f};
        }
        #pragma unroll
        for (int kk = 0; kk < 2; ++kk) {
            const int kb = kk * 64 + lk * 16;
            bf16x8 ah[2], al[2];
            #pragma unroll
            for (int mi = 0; mi < 2; ++mi) {
                int row = wr * 32 + mi * 16 + lr;
                ah[mi] = *(const bf16x8*)((const char*)Kh + LOFF(row, kb));
                al[mi] = *(const bf16x8*)((const char*)Kl + LOFF(row, kb));
            }
            #pragma unroll
            for (int mi = 0; mi < 2; ++mi)
            #pragma unroll
            for (int ni = 0; ni < 2; ++ni) {
                e[mi][ni] = MFMA(ah[mi], qh[ni][kk], e[mi][ni]);
                e[mi][ni] = MFMA(ah[mi], ql[ni][kk], e[mi][ni]);
                e[mi][ni] = MFMA(al[mi], qh[ni][kk], e[mi][ni]);
            }
        }
        #pragma unroll
        for (int mi = 0; mi < 2; ++mi)
        #pragma unroll
        for (int ni = 0; ni < 2; ++ni) {
            int n  = n0 + wn * 32 + ni * 16 + lr;
            int mg = m0 + wr * 32 + mi * 16 + lk * 4;
            float e0 = __expf(fminf(fmaxf(e[mi][ni][0], -1.f), 1.f));
            float e1 = __expf(fminf(fmaxf(e[mi][ni][1], -1.f), 1.f));
            float e2 = __expf(fminf(fmaxf(e[mi][ni][2], -1.f), 1.f));
            float e3 = __expf(fminf(fmaxf(e[mi][ni][3], -1.f), 1.f));
            z[ni] += e0 + e1 + e2 + e3;
            ushort4 p4;
            p4.x = f2bf(e0); p4.y = f2bf(e1); p4.z = f2bf(e2); p4.w = f2bf(e3);
            *(ushort4*)&Pws[((size_t)b * NP + n) * NP + mg] = p4;
        }
    }
    z[0] += __shfl_xor(z[0], 16); z[0] += __shfl_xor(z[0], 32);
    z[1] += __shfl_xor(z[1], 16); z[1] += __shfl_xor(z[1], 32);
    if (lk == 0) {
        atomicAdd(&zs[wn * 32 + lr], z[0]);
        atomicAdd(&zs[wn * 32 + 16 + lr], z[1]);
    }
    __syncthreads();
    if (tid < 64) Zws[(size_t)b * NP + n0 + tid] = zs[tid];
}

// ---------------------------------------------------------------------------
// Kernel C: out[b][c][n] = (sum_m P[n,m] * v[c,m]) / Z[n]
// tile 128n x 64c, K=1024 (16 steps).  grid (256, 8)
// ---------------------------------------------------------------------------
__global__ __launch_bounds__(256) void pvOut(
    const u16* __restrict__ Pws, const u16* __restrict__ vws,
    const float* __restrict__ Zws, float* __restrict__ out)
{
    __shared__ u16 Pt[128 * 64], Vt[64 * 64];
    __shared__ float zinv[128];
    const int tid = threadIdx.x;
    const int b = blockIdx.x >> 3, n0 = (blockIdx.x & 7) * 128;
    const int c0 = blockIdx.y * 64;
    const int wid = tid >> 6, lane = tid & 63;
    const int wm = wid >> 1, wn = wid & 1;
    const int lr = lane & 15, lk = lane >> 4;
    if (tid < 128) zinv[tid] = 1.0f / Zws[(size_t)b * NP + n0 + tid];

    f32x4 acc[4][2];
    #pragma unroll
    for (int i = 0; i < 4; ++i) {
        acc[i][0] = f32x4{0.f, 0.f, 0.f, 0.f};
        acc[i][1] = f32x4{0.f, 0.f, 0.f, 0.f};
    }

    for (int s = 0; s < 16; ++s) {
        const int m0 = s * 64;
        __syncthreads();
        #pragma unroll
        for (int it = 0; it < 4; ++it) {
            int idx = tid + it * 256;
            int row = idx >> 3, ch = idx & 7;
            const u16* src = Pws + ((size_t)b * NP + n0 + row) * NP + m0 + ch * 8;
            uint4 v = *(const uint4*)src;
            *(uint4*)((char*)Pt + LOFF(row, ch * 16)) = v;
        }
        #pragma unroll
        for (int it = 0; it < 2; ++it) {
            int idx = tid + it * 256;
            int row = idx >> 3, ch = idx & 7;
            const u16* src = vws + ((size_t)b * C_ + c0 + row) * NP + m0 + ch * 8;
            uint4 v = *(const uint4*)src;
            *(uint4*)((char*)Vt + LOFF(row, ch * 16)) = v;
        }
        __syncthreads();
        #pragma unroll
        for (int kk = 0; kk < 2; ++kk) {
            const int kb = kk * 64 + lk * 16;
            bf16x8 a[4], bfr[2];
            #pragma unroll
            for (int mi = 0; mi < 4; ++mi) {
                int row = wm * 64 + mi * 16 + lr;
                a[mi] = *(const bf16x8*)((const char*)Pt + LOFF(row, kb));
            }
            #pragma unroll
            for (int ni = 0; ni < 2; ++ni) {
                int row = wn * 32 + ni * 16 + lr;
                bfr[ni] = *(const bf16x8*)((const char*)Vt + LOFF(row, kb));
            }
            #pragma unroll
            for (int mi = 0; mi < 4; ++mi)
            #pragma unroll
            for (int ni = 0; ni < 2; ++ni)
                acc[mi][ni] = MFMA(a[mi], bfr[ni], acc[mi][ni]);
        }
    }
    #pragma unroll
    for (int mi = 0; mi < 4; ++mi)
    #pragma unroll
    for (int ni = 0; ni < 2; ++ni) {
        int nl0 = wm * 64 + mi * 16 + lk * 4;
        int c   = c0 + wn * 32 + ni * 16 + lr;
        float4 zi = *(float4*)&zinv[nl0];
        float4 o;
        o.x = acc[mi][ni][0] * zi.x;
        o.y = acc[mi][ni][1] * zi.y;
        o.z = acc[mi][ni][2] * zi.z;
        o.w = acc[mi][ni][3] * zi.w;
        *(float4*)&out[((size_t)b * C_ + c) * NP + n0 + nl0] = o;
    }
}

// ---------------------------------------------------------------------------
extern "C" void kernel_launch(void* const* d_in, const int* in_sizes, int n_in,
                              void* d_out, int out_size, void* d_ws, size_t ws_size,
                              hipStream_t stream) {
    const float* x  = (const float*)d_in[0];
    const float* w1 = (const float*)d_in[1];
    const float* wq = (const float*)d_in[2];
    const float* bq = (const float*)d_in[3];
    const float* wk = (const float*)d_in[4];
    const float* bk = (const float*)d_in[5];
    const float* wv = (const float*)d_in[6];
    const float* bv = (const float*)d_in[7];
    float* out = (float*)d_out;

    char* ws = (char*)d_ws;
    // layout (bytes):
    u16* xhi = (u16*)(ws + 0);            // 33,554,432
    u16* xlo = (u16*)(ws + 33554432ULL);  // 33,554,432
    u16* qhi = (u16*)(ws + 67108864ULL);  //  4,194,304
    u16* qlo = (u16*)(ws + 71303168ULL);
    u16* khi = (u16*)(ws + 75497472ULL);
    u16* klo = (u16*)(ws + 79691776ULL);
    u16* vws = (u16*)(ws + 83886080ULL);  // 33,554,432
    float* Zws = (float*)(ws + 117440512ULL); // 131,072
    u16* Pws = (u16*)(ws + 0);            // 67,108,864 — aliases xhi+xlo (dead by then)

    convA <<<dim3(512, 4), 256, 0, stream>>>(x, w1, xhi, xlo);
    projQK<<<512,          256, 0, stream>>>(xhi, xlo, wq, bq, wk, bk, qhi, qlo, khi, klo);
    projV <<<dim3(256, 8), 256, 0, stream>>>(xhi, wv, bv, vws);
    attnE <<<512,          256, 0, stream>>>(qhi, qlo, khi, klo, Pws, Zws);
    pvOut <<<dim3(256, 8), 256, 0, stream>>>(Pws, vws, Zws, out);
}

// Round 4
// 387.403 us; speedup vs baseline: 6.9737x; 1.2461x over previous
//
#include <hip/hip_runtime.h>
#include <hip/hip_bf16.h>
#include <cstdint>

typedef unsigned short u16;
typedef unsigned int u32;
typedef __attribute__((ext_vector_type(8))) short bf16x8;
typedef __attribute__((ext_vector_type(4))) float f32x4;

#define B_   32
#define C_   512
#define CQK  64
#define NP   1024

// byte offset into a [rows][64 bf16] LDS tile (row stride 128 B, 16B-slot XOR swizzle)
#define LOFF(row, kb) (((row) << 7) + ((kb) ^ (((row) & 7) << 4)))

__device__ __forceinline__ u16 f2bf(float f) {
    union { __hip_bfloat16 b; u16 u; } cv;
    cv.b = __float2bfloat16(f);
    return cv.u;
}
__device__ __forceinline__ float bf2f(u16 h) {
    return __uint_as_float(((u32)h) << 16);
}

// write 16 bf16 values into tile at (row, kb..kb+31 bytes) honoring swizzle
__device__ __forceinline__ void put16(u16* tile, int row, int kb, const u16* v) {
    char* p = (char*)tile;
    *(ushort4*)(p + LOFF(row, kb))          = *(const ushort4*)(v + 0);
    *(ushort4*)(p + LOFF(row, kb) + 8)      = *(const ushort4*)(v + 4);
    *(ushort4*)(p + LOFF(row, kb + 16))     = *(const ushort4*)(v + 8);
    *(ushort4*)(p + LOFF(row, kb + 16) + 8) = *(const ushort4*)(v + 12);
}

// load 16 fp32, produce hi/lo bf16 splits (hardware cvt)
__device__ __forceinline__ void split16(const float* src, u16* h, u16* l) {
    float f[16];
    *(float4*)&f[0]  = *(const float4*)(src + 0);
    *(float4*)&f[4]  = *(const float4*)(src + 4);
    *(float4*)&f[8]  = *(const float4*)(src + 8);
    *(float4*)&f[12] = *(const float4*)(src + 12);
    #pragma unroll
    for (int i = 0; i < 16; ++i) {
        h[i] = f2bf(f[i]);
        l[i] = f2bf(f[i] - bf2f(h[i]));
    }
}
__device__ __forceinline__ void split8(const float* src, u16* h, u16* l) {
    float f[8];
    *(float4*)&f[0] = *(const float4*)(src);
    *(float4*)&f[4] = *(const float4*)(src + 4);
    #pragma unroll
    for (int i = 0; i < 8; ++i) {
        h[i] = f2bf(f[i]);
        l[i] = f2bf(f[i] - bf2f(h[i]));
    }
}

#define MFMA(a, b, c) __builtin_amdgcn_mfma_f32_16x16x32_bf16((a), (b), (c), 0, 0, 0)

// ---------------------------------------------------------------------------
// Kernel 0: weight prepack (once per launch).  w1 -> hi/lo bf16 [512][768],
// wq;wk -> hi/lo [128][512], wv -> bf16 [512][512].  grid 352x256.
// ---------------------------------------------------------------------------
__global__ __launch_bounds__(256) void prepack(
    const float* __restrict__ w1, const float* __restrict__ wq,
    const float* __restrict__ wk, const float* __restrict__ wv,
    u16* __restrict__ w1h, u16* __restrict__ w1l,
    u16* __restrict__ wqkh, u16* __restrict__ wqkl,
    u16* __restrict__ wvb)
{
    int t = blockIdx.x * 256 + threadIdx.x;
    if (t < 49152) {                       // w1: 512*768 = 393216 elems / 8
        int e = t * 8;
        u16 h[8], l[8];
        split8(w1 + e, h, l);
        *(uint4*)(w1h + e) = *(const uint4*)h;
        *(uint4*)(w1l + e) = *(const uint4*)l;
    } else if (t < 57344) {                // wq;wk: 2*64*512 = 65536 elems / 8
        int e = (t - 49152) * 8;
        const float* src = (e < 32768) ? (wq + e) : (wk + (e - 32768));
        u16 h[8], l[8];
        split8(src, h, l);
        *(uint4*)(wqkh + e) = *(const uint4*)h;
        *(uint4*)(wqkl + e) = *(const uint4*)l;
    } else if (t < 90112) {                // wv: 512*512 = 262144 elems / 8
        int e = (t - 57344) * 8;
        float f[8];
        *(float4*)&f[0] = *(const float4*)(wv + e);
        *(float4*)&f[4] = *(const float4*)(wv + e + 4);
        u16 h[8];
        #pragma unroll
        for (int i = 0; i < 8; ++i) h[i] = f2bf(f[i]);
        *(uint4*)(wvb + e) = *(const uint4*)h;
    }
}

// ---------------------------------------------------------------------------
// Kernel A: patchify conv as GEMM, split-bf16.  D[cout, n] = W1[cout, k] * Patch[k, n]
// tile 128m x 64n, BK=64, K=768 (12 steps).  grid (512, 4)
// A staged by copy from prepacked w1h/w1l; B = im2col gather + hw split.
// ---------------------------------------------------------------------------
__global__ __launch_bounds__(256) void convA(
    const float* __restrict__ x,
    const u16* __restrict__ w1h, const u16* __restrict__ w1l,
    u16* __restrict__ xhi, u16* __restrict__ xlo)
{
    __shared__ u16 Ah[128 * 64], Al[128 * 64], Bh[64 * 64], Bl[64 * 64];
    const int tid = threadIdx.x;
    const int b = blockIdx.x >> 4, nt = blockIdx.x & 15;
    const int n0 = nt * 64, ph0 = nt * 2;
    const int m0 = blockIdx.y * 128;
    const int wid = tid >> 6, lane = tid & 63;
    const int wm = wid >> 1, wn = wid & 1;
    const int lr = lane & 15, lk = lane >> 4;

    f32x4 acc[4][2];
    #pragma unroll
    for (int i = 0; i < 4; ++i) {
        acc[i][0] = f32x4{0.f, 0.f, 0.f, 0.f};
        acc[i][1] = f32x4{0.f, 0.f, 0.f, 0.f};
    }

    for (int s = 0; s < 12; ++s) {
        const int k0 = s * 64;
        const int ci = s >> 2, ky0 = (s & 3) * 4;
        __syncthreads();
        // --- stage A: copy prepacked hi/lo, 128 rows x 64 k
        #pragma unroll
        for (int it = 0; it < 4; ++it) {
            int idx = tid + it * 256;           // 1024 = 128 rows x 8 slots
            int row = idx >> 3, ch = idx & 7;
            size_t off = (size_t)(m0 + row) * 768 + k0 + ch * 8;
            *(uint4*)((char*)Ah + LOFF(row, ch * 16)) = *(const uint4*)(w1h + off);
            *(uint4*)((char*)Al + LOFF(row, ch * 16)) = *(const uint4*)(w1l + off);
        }
        // --- stage B (im2col gather, fp32 -> hi/lo) : 64 n x 64 k
        {
            int r = tid >> 5, phl = r >> 2, kyl = r & 3;
            int f0 = (tid & 31) * 16;
            int y = (ph0 + phl) * 16 + ky0 + kyl;
            const float* src = x + (((size_t)b * 3 + ci) * 512 + y) * 512 + f0;
            int n = phl * 32 + (f0 >> 4);
            u16 h[16], l[16];
            split16(src, h, l);
            put16(Bh, n, kyl * 32, h);
            put16(Bl, n, kyl * 32, l);
        }
        __syncthreads();
        #pragma unroll
        for (int kk = 0; kk < 2; ++kk) {
            const int kb = kk * 64 + lk * 16;
            bf16x8 ah[4], al[4], bh[2], bl[2];
            #pragma unroll
            for (int mi = 0; mi < 4; ++mi) {
                int row = wm * 64 + mi * 16 + lr;
                ah[mi] = *(const bf16x8*)((const char*)Ah + LOFF(row, kb));
                al[mi] = *(const bf16x8*)((const char*)Al + LOFF(row, kb));
            }
            #pragma unroll
            for (int ni = 0; ni < 2; ++ni) {
                int row = wn * 32 + ni * 16 + lr;
                bh[ni] = *(const bf16x8*)((const char*)Bh + LOFF(row, kb));
                bl[ni] = *(const bf16x8*)((const char*)Bl + LOFF(row, kb));
            }
            #pragma unroll
            for (int mi = 0; mi < 4; ++mi)
            #pragma unroll
            for (int ni = 0; ni < 2; ++ni) {
                acc[mi][ni] = MFMA(ah[mi], bh[ni], acc[mi][ni]);
                acc[mi][ni] = MFMA(ah[mi], bl[ni], acc[mi][ni]);
                acc[mi][ni] = MFMA(al[mi], bh[ni], acc[mi][ni]);
            }
        }
    }
    // epilogue: split + store to xhi/xlo[b][n][c]
    #pragma unroll
    for (int mi = 0; mi < 4; ++mi)
    #pragma unroll
    for (int ni = 0; ni < 2; ++ni) {
        int c0 = m0 + wm * 64 + mi * 16 + lk * 4;
        int n  = n0 + wn * 32 + ni * 16 + lr;
        ushort4 h4, l4;
        float v0 = acc[mi][ni][0], v1 = acc[mi][ni][1];
        float v2 = acc[mi][ni][2], v3 = acc[mi][ni][3];
        h4.x = f2bf(v0); l4.x = f2bf(v0 - bf2f(h4.x));
        h4.y = f2bf(v1); l4.y = f2bf(v1 - bf2f(h4.y));
        h4.z = f2bf(v2); l4.z = f2bf(v2 - bf2f(h4.z));
        h4.w = f2bf(v3); l4.w = f2bf(v3 - bf2f(h4.w));
        size_t base = ((size_t)b * NP + n) * C_ + c0;
        *(ushort4*)&xhi[base] = h4;
        *(ushort4*)&xlo[base] = l4;
    }
}

// ---------------------------------------------------------------------------
// Kernel P1: q/k projection, split-bf16.  rows 0..63 = q, 64..127 = k.
// tile 128m x 64n, K=512 (8 steps).  grid 512.  W staged by copy (prepacked).
// ---------------------------------------------------------------------------
__global__ __launch_bounds__(256) void projQK(
    const u16* __restrict__ xhi, const u16* __restrict__ xlo,
    const u16* __restrict__ wqkh, const u16* __restrict__ wqkl,
    const float* __restrict__ bq, const float* __restrict__ bk,
    u16* __restrict__ qhi, u16* __restrict__ qlo,
    u16* __restrict__ khi, u16* __restrict__ klo)
{
    __shared__ u16 Wh[128 * 64], Wl[128 * 64], Xh[64 * 64], Xl[64 * 64];
    __shared__ float biasS[128];
    const int tid = threadIdx.x;
    const int b = blockIdx.x >> 4, n0 = (blockIdx.x & 15) * 64;
    const int wid = tid >> 6, lane = tid & 63;
    const int wm = wid >> 1, wn = wid & 1;
    const int lr = lane & 15, lk = lane >> 4;
    if (tid < 128) biasS[tid] = (tid < 64) ? bq[tid] : bk[tid - 64];

    f32x4 acc[4][2];
    #pragma unroll
    for (int i = 0; i < 4; ++i) {
        acc[i][0] = f32x4{0.f, 0.f, 0.f, 0.f};
        acc[i][1] = f32x4{0.f, 0.f, 0.f, 0.f};
    }

    for (int s = 0; s < 8; ++s) {
        const int k0 = s * 64;
        __syncthreads();
        #pragma unroll
        for (int it = 0; it < 4; ++it) {
            int idx = tid + it * 256;           // 128 rows x 8 slots
            int row = idx >> 3, ch = idx & 7;
            size_t off = (size_t)row * C_ + k0 + ch * 8;
            *(uint4*)((char*)Wh + LOFF(row, ch * 16)) = *(const uint4*)(wqkh + off);
            *(uint4*)((char*)Wl + LOFF(row, ch * 16)) = *(const uint4*)(wqkl + off);
        }
        #pragma unroll
        for (int it = 0; it < 4; ++it) {
            int idx = tid + it * 256;
            int sel = idx >> 9, u = idx & 511;
            int row = u >> 3, ch = u & 7;
            const u16* src = (sel ? xlo : xhi) + ((size_t)b * NP + n0 + row) * C_ + k0 + ch * 8;
            uint4 v = *(const uint4*)src;
            *(uint4*)((char*)(sel ? Xl : Xh) + LOFF(row, ch * 16)) = v;
        }
        __syncthreads();
        #pragma unroll
        for (int kk = 0; kk < 2; ++kk) {
            const int kb = kk * 64 + lk * 16;
            bf16x8 ah[4], al[4], bh[2], bl[2];
            #pragma unroll
            for (int mi = 0; mi < 4; ++mi) {
                int row = wm * 64 + mi * 16 + lr;
                ah[mi] = *(const bf16x8*)((const char*)Wh + LOFF(row, kb));
                al[mi] = *(const bf16x8*)((const char*)Wl + LOFF(row, kb));
            }
            #pragma unroll
            for (int ni = 0; ni < 2; ++ni) {
                int row = wn * 32 + ni * 16 + lr;
                bh[ni] = *(const bf16x8*)((const char*)Xh + LOFF(row, kb));
                bl[ni] = *(const bf16x8*)((const char*)Xl + LOFF(row, kb));
            }
            #pragma unroll
            for (int mi = 0; mi < 4; ++mi)
            #pragma unroll
            for (int ni = 0; ni < 2; ++ni) {
                acc[mi][ni] = MFMA(ah[mi], bh[ni], acc[mi][ni]);
                acc[mi][ni] = MFMA(ah[mi], bl[ni], acc[mi][ni]);
                acc[mi][ni] = MFMA(al[mi], bh[ni], acc[mi][ni]);
            }
        }
    }
    #pragma unroll
    for (int mi = 0; mi < 4; ++mi)
    #pragma unroll
    for (int ni = 0; ni < 2; ++ni) {
        int j0 = wm * 64 + mi * 16 + lk * 4;
        int n  = n0 + wn * 32 + ni * 16 + lr;
        float4 bb = *(float4*)&biasS[j0];
        float v0 = acc[mi][ni][0] + bb.x, v1 = acc[mi][ni][1] + bb.y;
        float v2 = acc[mi][ni][2] + bb.z, v3 = acc[mi][ni][3] + bb.w;
        ushort4 h4, l4;
        h4.x = f2bf(v0); l4.x = f2bf(v0 - bf2f(h4.x));
        h4.y = f2bf(v1); l4.y = f2bf(v1 - bf2f(h4.y));
        h4.z = f2bf(v2); l4.z = f2bf(v2 - bf2f(h4.z));
        h4.w = f2bf(v3); l4.w = f2bf(v3 - bf2f(h4.w));
        if (wm == 0) {
            size_t base = ((size_t)b * NP + n) * CQK + j0;
            *(ushort4*)&qhi[base] = h4;
            *(ushort4*)&qlo[base] = l4;
        } else {
            size_t base = ((size_t)b * NP + n) * CQK + (j0 - 64);
            *(ushort4*)&khi[base] = h4;
            *(ushort4*)&klo[base] = l4;
        }
    }
}

// ---------------------------------------------------------------------------
// Kernel P2: v projection, single bf16.  tile 128n x 64cout, K=512 (8 steps).
// grid 2048 (XCD-grouped: 4 batches per XCD).  W staged by copy (prepacked).
// ---------------------------------------------------------------------------
__global__ __launch_bounds__(256) void projV(
    const u16* __restrict__ xhi, const u16* __restrict__ wvb,
    const float* __restrict__ bv, u16* __restrict__ vws)
{
    __shared__ u16 Xt[128 * 64], Wt[64 * 64];
    __shared__ float biasS[64];
    const int tid = threadIdx.x;
    const int bid = blockIdx.x;
    const int xcd = bid & 7, slot = bid >> 3;
    const int b = xcd * 4 + (slot >> 6);
    const int r = slot & 63;
    const int n0 = (r >> 3) * 128;
    const int c0 = (r & 7) * 64;
    const int wid = tid >> 6, lane = tid & 63;
    const int wm = wid >> 1, wn = wid & 1;
    const int lr = lane & 15, lk = lane >> 4;
    if (tid < 64) biasS[tid] = bv[c0 + tid];

    f32x4 acc[4][2];
    #pragma unroll
    for (int i = 0; i < 4; ++i) {
        acc[i][0] = f32x4{0.f, 0.f, 0.f, 0.f};
        acc[i][1] = f32x4{0.f, 0.f, 0.f, 0.f};
    }

    for (int s = 0; s < 8; ++s) {
        const int k0 = s * 64;
        __syncthreads();
        #pragma unroll
        for (int it = 0; it < 4; ++it) {
            int idx = tid + it * 256;
            int row = idx >> 3, ch = idx & 7;
            const u16* src = xhi + ((size_t)b * NP + n0 + row) * C_ + k0 + ch * 8;
            uint4 v = *(const uint4*)src;
            *(uint4*)((char*)Xt + LOFF(row, ch * 16)) = v;
        }
        #pragma unroll
        for (int it = 0; it < 2; ++it) {
            int idx = tid + it * 256;           // 64 rows x 8 slots
            int row = idx >> 3, ch = idx & 7;
            const u16* src = wvb + (size_t)(c0 + row) * C_ + k0 + ch * 8;
            *(uint4*)((char*)Wt + LOFF(row, ch * 16)) = *(const uint4*)src;
        }
        __syncthreads();
        #pragma unroll
        for (int kk = 0; kk < 2; ++kk) {
            const int kb = kk * 64 + lk * 16;
            bf16x8 a[4], bfr[2];
            #pragma unroll
            for (int mi = 0; mi < 4; ++mi) {
                int row = wm * 64 + mi * 16 + lr;
                a[mi] = *(const bf16x8*)((const char*)Xt + LOFF(row, kb));
            }
            #pragma unroll
            for (int ni = 0; ni < 2; ++ni) {
                int row = wn * 32 + ni * 16 + lr;
                bfr[ni] = *(const bf16x8*)((const char*)Wt + LOFF(row, kb));
            }
            #pragma unroll
            for (int mi = 0; mi < 4; ++mi)
            #pragma unroll
            for (int ni = 0; ni < 2; ++ni)
                acc[mi][ni] = MFMA(a[mi], bfr[ni], acc[mi][ni]);
        }
    }
    #pragma unroll
    for (int mi = 0; mi < 4; ++mi)
    #pragma unroll
    for (int ni = 0; ni < 2; ++ni) {
        int nr0 = n0 + wm * 64 + mi * 16 + lk * 4;
        int c   = c0 + wn * 32 + ni * 16 + lr;
        float bias = biasS[wn * 32 + ni * 16 + lr];
        ushort4 h4;
        h4.x = f2bf(acc[mi][ni][0] + bias);
        h4.y = f2bf(acc[mi][ni][1] + bias);
        h4.z = f2bf(acc[mi][ni][2] + bias);
        h4.w = f2bf(acc[mi][ni][3] + bias);
        *(ushort4*)&vws[((size_t)b * C_ + c) * NP + nr0] = h4;
    }
}

// ---------------------------------------------------------------------------
// Kernel B: E^T[m,n] = k_m . q_n  (split-bf16, swapped operands), clip, exp,
// running Z[n]; writes unnormalized P[b][n][m] bf16 + Z[b][n] fp32.  grid 512.
// ---------------------------------------------------------------------------
__global__ __launch_bounds__(256) void attnE(
    const u16* __restrict__ qhi, const u16* __restrict__ qlo,
    const u16* __restrict__ khi, const u16* __restrict__ klo,
    u16* __restrict__ Pws, float* __restrict__ Zws)
{
    __shared__ u16 Kh[64 * 64], Kl[64 * 64], Qh[64 * 64], Ql[64 * 64];
    __shared__ float zs[64];
    const int tid = threadIdx.x;
    const int b = blockIdx.x >> 4, n0 = (blockIdx.x & 15) * 64;
    const int wid = tid >> 6, lane = tid & 63;
    const int wr = wid >> 1, wn = wid & 1;
    const int lr = lane & 15, lk = lane >> 4;
    if (tid < 64) zs[tid] = 0.f;

    // stage Q (hi+lo) once
    #pragma unroll
    for (int it = 0; it < 4; ++it) {
        int idx = tid + it * 256;
        int sel = idx >> 9, u = idx & 511;
        int row = u >> 3, ch = u & 7;
        const u16* src = (sel ? qlo : qhi) + ((size_t)b * NP + n0 + row) * CQK + ch * 8;
        uint4 v = *(const uint4*)src;
        *(uint4*)((char*)(sel ? Ql : Qh) + LOFF(row, ch * 16)) = v;
    }
    __syncthreads();
    // hoist Q frags to registers
    bf16x8 qh[2][2], ql[2][2];
    #pragma unroll
    for (int ni = 0; ni < 2; ++ni)
    #pragma unroll
    for (int kk = 0; kk < 2; ++kk) {
        int row = wn * 32 + ni * 16 + lr;
        int kb = kk * 64 + lk * 16;
        qh[ni][kk] = *(const bf16x8*)((const char*)Qh + LOFF(row, kb));
        ql[ni][kk] = *(const bf16x8*)((const char*)Ql + LOFF(row, kb));
    }

    float z[2] = {0.f, 0.f};
    for (int ms = 0; ms < 16; ++ms) {
        const int m0 = ms * 64;
        __syncthreads();
        #pragma unroll
        for (int it = 0; it < 4; ++it) {
            int idx = tid + it * 256;
            int sel = idx >> 9, u = idx & 511;
            int row = u >> 3, ch = u & 7;
            const u16* src = (sel ? klo : khi) + ((size_t)b * NP + m0 + row) * CQK + ch * 8;
            uint4 v = *(const uint4*)src;
            *(uint4*)((char*)(sel ? Kl : Kh) + LOFF(row, ch * 16)) = v;
        }
        __syncthreads();
        f32x4 e[2][2];
        #pragma unroll
        for (int i = 0; i < 2; ++i) {
            e[i][0] = f32x4{0.f, 0.f, 0.f, 0.f};
            e[i][1] = f32x4{0.f, 0.f, 0.f, 0.f};
        }
        #pragma unroll
        for (int kk = 0; kk < 2; ++kk) {
            const int kb = kk * 64 + lk * 16;
            bf16x8 ah[2], al[2];
            #pragma unroll
            for (int mi = 0; mi < 2; ++mi) {
                int row = wr * 32 + mi * 16 + lr;
                ah[mi] = *(const bf16x8*)((const char*)Kh + LOFF(row, kb));
                al[mi] = *(const bf16x8*)((const char*)Kl + LOFF(row, kb));
            }
            #pragma unroll
            for (int mi = 0; mi < 2; ++mi)
            #pragma unroll
            for (int ni = 0; ni < 2; ++ni) {
                e[mi][ni] = MFMA(ah[mi], qh[ni][kk], e[mi][ni]);
                e[mi][ni] = MFMA(ah[mi], ql[ni][kk], e[mi][ni]);
                e[mi][ni] = MFMA(al[mi], qh[ni][kk], e[mi][ni]);
            }
        }
        #pragma unroll
        for (int mi = 0; mi < 2; ++mi)
        #pragma unroll
        for (int ni = 0; ni < 2; ++ni) {
            int n  = n0 + wn * 32 + ni * 16 + lr;
            int mg = m0 + wr * 32 + mi * 16 + lk * 4;
            float e0 = __expf(fminf(fmaxf(e[mi][ni][0], -1.f), 1.f));
            float e1 = __expf(fminf(fmaxf(e[mi][ni][1], -1.f), 1.f));
            float e2 = __expf(fminf(fmaxf(e[mi][ni][2], -1.f), 1.f));
            float e3 = __expf(fminf(fmaxf(e[mi][ni][3], -1.f), 1.f));
            z[ni] += e0 + e1 + e2 + e3;
            ushort4 p4;
            p4.x = f2bf(e0); p4.y = f2bf(e1); p4.z = f2bf(e2); p4.w = f2bf(e3);
            *(ushort4*)&Pws[((size_t)b * NP + n) * NP + mg] = p4;
        }
    }
    z[0] += __shfl_xor(z[0], 16); z[0] += __shfl_xor(z[0], 32);
    z[1] += __shfl_xor(z[1], 16); z[1] += __shfl_xor(z[1], 32);
    if (lk == 0) {
        atomicAdd(&zs[wn * 32 + lr], z[0]);
        atomicAdd(&zs[wn * 32 + 16 + lr], z[1]);
    }
    __syncthreads();
    if (tid < 64) Zws[(size_t)b * NP + n0 + tid] = zs[tid];
}

// ---------------------------------------------------------------------------
// Kernel C: out[b][c][n] = (sum_m P[n,m] * v[c,m]) / Z[n]
// tile 128n x 64c, K=1024 (16 steps).  grid 2048 (XCD-grouped).
// ---------------------------------------------------------------------------
__global__ __launch_bounds__(256) void pvOut(
    const u16* __restrict__ Pws, const u16* __restrict__ vws,
    const float* __restrict__ Zws, float* __restrict__ out)
{
    __shared__ u16 Pt[128 * 64], Vt[64 * 64];
    __shared__ float zinv[128];
    const int tid = threadIdx.x;
    const int bid = blockIdx.x;
    const int xcd = bid & 7, slot = bid >> 3;
    const int b = xcd * 4 + (slot >> 6);
    const int r = slot & 63;
    const int n0 = (r >> 3) * 128;
    const int c0 = (r & 7) * 64;
    const int wid = tid >> 6, lane = tid & 63;
    const int wm = wid >> 1, wn = wid & 1;
    const int lr = lane & 15, lk = lane >> 4;
    if (tid < 128) zinv[tid] = 1.0f / Zws[(size_t)b * NP + n0 + tid];

    f32x4 acc[4][2];
    #pragma unroll
    for (int i = 0; i < 4; ++i) {
        acc[i][0] = f32x4{0.f, 0.f, 0.f, 0.f};
        acc[i][1] = f32x4{0.f, 0.f, 0.f, 0.f};
    }

    for (int s = 0; s < 16; ++s) {
        const int m0 = s * 64;
        __syncthreads();
        #pragma unroll
        for (int it = 0; it < 4; ++it) {
            int idx = tid + it * 256;
            int row = idx >> 3, ch = idx & 7;
            const u16* src = Pws + ((size_t)b * NP + n0 + row) * NP + m0 + ch * 8;
            uint4 v = *(const uint4*)src;
            *(uint4*)((char*)Pt + LOFF(row, ch * 16)) = v;
        }
        #pragma unroll
        for (int it = 0; it < 2; ++it) {
            int idx = tid + it * 256;
            int row = idx >> 3, ch = idx & 7;
            const u16* src = vws + ((size_t)b * C_ + c0 + row) * NP + m0 + ch * 8;
            uint4 v = *(const uint4*)src;
            *(uint4*)((char*)Vt + LOFF(row, ch * 16)) = v;
        }
        __syncthreads();
        #pragma unroll
        for (int kk = 0; kk < 2; ++kk) {
            const int kb = kk * 64 + lk * 16;
            bf16x8 a[4], bfr[2];
            #pragma unroll
            for (int mi = 0; mi < 4; ++mi) {
                int row = wm * 64 + mi * 16 + lr;
                a[mi] = *(const bf16x8*)((const char*)Pt + LOFF(row, kb));
            }
            #pragma unroll
            for (int ni = 0; ni < 2; ++ni) {
                int row = wn * 32 + ni * 16 + lr;
                bfr[ni] = *(const bf16x8*)((const char*)Vt + LOFF(row, kb));
            }
            #pragma unroll
            for (int mi = 0; mi < 4; ++mi)
            #pragma unroll
            for (int ni = 0; ni < 2; ++ni)
                acc[mi][ni] = MFMA(a[mi], bfr[ni], acc[mi][ni]);
        }
    }
    #pragma unroll
    for (int mi = 0; mi < 4; ++mi)
    #pragma unroll
    for (int ni = 0; ni < 2; ++ni) {
        int nl0 = wm * 64 + mi * 16 + lk * 4;
        int c   = c0 + wn * 32 + ni * 16 + lr;
        float4 zi = *(float4*)&zinv[nl0];
        float4 o;
        o.x = acc[mi][ni][0] * zi.x;
        o.y = acc[mi][ni][1] * zi.y;
        o.z = acc[mi][ni][2] * zi.z;
        o.w = acc[mi][ni][3] * zi.w;
        *(float4*)&out[((size_t)b * C_ + c) * NP + n0 + nl0] = o;
    }
}

// ---------------------------------------------------------------------------
extern "C" void kernel_launch(void* const* d_in, const int* in_sizes, int n_in,
                              void* d_out, int out_size, void* d_ws, size_t ws_size,
                              hipStream_t stream) {
    const float* x  = (const float*)d_in[0];
    const float* w1 = (const float*)d_in[1];
    const float* wq = (const float*)d_in[2];
    const float* bq = (const float*)d_in[3];
    const float* wk = (const float*)d_in[4];
    const float* bk = (const float*)d_in[5];
    const float* wv = (const float*)d_in[6];
    const float* bv = (const float*)d_in[7];
    float* out = (float*)d_out;

    char* ws = (char*)d_ws;
    // workspace layout (bytes), proven footprint <= 117,571,584:
    u16* xhi = (u16*)(ws + 0);            // 33,554,432
    u16* xlo = (u16*)(ws + 33554432ULL);  // 33,554,432
    u16* Pws = (u16*)(ws + 0);            // 67,108,864 — aliases xhi+xlo (dead by attnE)
    u16* qhi = (u16*)(ws + 67108864ULL);  //  4,194,304
    u16* qlo = (u16*)(ws + 71303168ULL);
    u16* khi = (u16*)(ws + 75497472ULL);
    u16* klo = (u16*)(ws + 79691776ULL);
    u16* vws = (u16*)(ws + 83886080ULL);  // 33,554,432
    float* Zws = (float*)(ws + 117440512ULL); // 131,072  (ends 117,571,584)

    // prepacked weights live in d_out scratch (dead region until pvOut,
    // which overwrites all of d_out in its epilogue):
    char* sc = (char*)d_out;
    u16* w1h  = (u16*)(sc + 0);           // 786,432
    u16* w1l  = (u16*)(sc + 786432);      // 786,432
    u16* wqkh = (u16*)(sc + 1572864);     // 131,072
    u16* wqkl = (u16*)(sc + 1703936);     // 131,072
    u16* wvb  = (u16*)(sc + 1835008);     // 524,288  (ends 2,359,296 << 64 MB)

    prepack<<<352, 256, 0, stream>>>(w1, wq, wk, wv, w1h, w1l, wqkh, wqkl, wvb);
    convA <<<dim3(512, 4), 256, 0, stream>>>(x, w1h, w1l, xhi, xlo);
    projQK<<<512,  256, 0, stream>>>(xhi, xlo, wqkh, wqkl, bq, bk, qhi, qlo, khi, klo);
    projV <<<2048, 256, 0, stream>>>(xhi, wvb, bv, vws);
    attnE <<<512,  256, 0, stream>>>(qhi, qlo, khi, klo, Pws, Zws);
    pvOut <<<2048, 256, 0, stream>>>(Pws, vws, Zws, out);
}

// Round 6
// 383.480 us; speedup vs baseline: 7.0450x; 1.0102x over previous
//
#include <hip/hip_runtime.h>
#include <hip/hip_bf16.h>
#include <cstdint>

typedef unsigned short u16;
typedef unsigned int u32;
typedef __attribute__((ext_vector_type(8))) short bf16x8;
typedef __attribute__((ext_vector_type(4))) float f32x4;

#define B_   32
#define C_   512
#define CQK  64
#define NP   1024

// byte offset into a [rows][64 bf16] LDS tile (row stride 128 B, 16B-slot XOR swizzle)
#define LOFF(row, kb) (((row) << 7) + ((kb) ^ (((row) & 7) << 4)))

__device__ __forceinline__ u16 f2bf(float f) {
    union { __hip_bfloat16 b; u16 u; } cv;
    cv.b = __float2bfloat16(f);
    return cv.u;
}
__device__ __forceinline__ float bf2f(u16 h) {
    return __uint_as_float(((u32)h) << 16);
}

// write 16 bf16 values into tile at (row, kb..kb+31 bytes) honoring swizzle
__device__ __forceinline__ void put16(u16* tile, int row, int kb, const u16* v) {
    char* p = (char*)tile;
    *(ushort4*)(p + LOFF(row, kb))          = *(const ushort4*)(v + 0);
    *(ushort4*)(p + LOFF(row, kb) + 8)      = *(const ushort4*)(v + 4);
    *(ushort4*)(p + LOFF(row, kb + 16))     = *(const ushort4*)(v + 8);
    *(ushort4*)(p + LOFF(row, kb + 16) + 8) = *(const ushort4*)(v + 12);
}

// load 16 fp32, produce hi/lo bf16 splits (hardware cvt)
__device__ __forceinline__ void split16(const float* src, u16* h, u16* l) {
    float f[16];
    *(float4*)&f[0]  = *(const float4*)(src + 0);
    *(float4*)&f[4]  = *(const float4*)(src + 4);
    *(float4*)&f[8]  = *(const float4*)(src + 8);
    *(float4*)&f[12] = *(const float4*)(src + 12);
    #pragma unroll
    for (int i = 0; i < 16; ++i) {
        h[i] = f2bf(f[i]);
        l[i] = f2bf(f[i] - bf2f(h[i]));
    }
}
__device__ __forceinline__ void split8(const float* src, u16* h, u16* l) {
    float f[8];
    *(float4*)&f[0] = *(const float4*)(src);
    *(float4*)&f[4] = *(const float4*)(src + 4);
    #pragma unroll
    for (int i = 0; i < 8; ++i) {
        h[i] = f2bf(f[i]);
        l[i] = f2bf(f[i] - bf2f(h[i]));
    }
}

#define MFMA(a, b, c) __builtin_amdgcn_mfma_f32_16x16x32_bf16((a), (b), (c), 0, 0, 0)

// ---------------------------------------------------------------------------
// Kernel 0: weight prepack (once per launch).  w1 -> hi/lo bf16 [512][768],
// wq;wk -> hi/lo [128][512], wv -> bf16 [512][512].  grid 352x256.
// ---------------------------------------------------------------------------
__global__ __launch_bounds__(256) void prepack(
    const float* __restrict__ w1, const float* __restrict__ wq,
    const float* __restrict__ wk, const float* __restrict__ wv,
    u16* __restrict__ w1h, u16* __restrict__ w1l,
    u16* __restrict__ wqkh, u16* __restrict__ wqkl,
    u16* __restrict__ wvb)
{
    int t = blockIdx.x * 256 + threadIdx.x;
    if (t < 49152) {                       // w1: 512*768 = 393216 elems / 8
        int e = t * 8;
        u16 h[8], l[8];
        split8(w1 + e, h, l);
        *(uint4*)(w1h + e) = *(const uint4*)h;
        *(uint4*)(w1l + e) = *(const uint4*)l;
    } else if (t < 57344) {                // wq;wk: 2*64*512 = 65536 elems / 8
        int e = (t - 49152) * 8;
        const float* src = (e < 32768) ? (wq + e) : (wk + (e - 32768));
        u16 h[8], l[8];
        split8(src, h, l);
        *(uint4*)(wqkh + e) = *(const uint4*)h;
        *(uint4*)(wqkl + e) = *(const uint4*)l;
    } else if (t < 90112) {                // wv: 512*512 = 262144 elems / 8
        int e = (t - 57344) * 8;
        float f[8];
        *(float4*)&f[0] = *(const float4*)(wv + e);
        *(float4*)&f[4] = *(const float4*)(wv + e + 4);
        u16 h[8];
        #pragma unroll
        for (int i = 0; i < 8; ++i) h[i] = f2bf(f[i]);
        *(uint4*)(wvb + e) = *(const uint4*)h;
    }
}

// ---------------------------------------------------------------------------
// Kernel A: patchify conv as GEMM, split-bf16.  D[cout, n] = W1[cout, k] * Patch[k, n]
// tile 128m x 128n, BK=64, K=768 (12 steps).  grid 1024, XCD-chunked so the
// 4 m-tiles of one (b,nt) patch set share an XCD (L2 reuse of x).
// ---------------------------------------------------------------------------
__global__ __launch_bounds__(256) void convA(
    const float* __restrict__ x,
    const u16* __restrict__ w1h, const u16* __restrict__ w1l,
    u16* __restrict__ xhi, u16* __restrict__ xlo)
{
    __shared__ u16 Ah[128 * 64], Al[128 * 64], Bh[128 * 64], Bl[128 * 64];
    const int tid = threadIdx.x;
    const int bid = blockIdx.x;
    const int xcd = bid & 7, slot = bid >> 3;      // blocks round-robin XCDs
    const int grp = slot >> 2, mt = slot & 3;      // 4 m-tiles consecutive per XCD
    const int gg = xcd * 32 + grp;                 // 0..255 = (b, nt)
    const int b = gg >> 3, nt = gg & 7;
    const int n0 = nt * 128, ph0 = nt * 4;
    const int m0 = mt * 128;
    const int wid = tid >> 6, lane = tid & 63;
    const int wm = wid >> 1, wn = wid & 1;
    const int lr = lane & 15, lk = lane >> 4;

    f32x4 acc[4][4];
    #pragma unroll
    for (int i = 0; i < 4; ++i)
    #pragma unroll
    for (int j = 0; j < 4; ++j) acc[i][j] = f32x4{0.f, 0.f, 0.f, 0.f};

    for (int s = 0; s < 12; ++s) {
        const int k0 = s * 64;
        const int ci = s >> 2, ky0 = (s & 3) * 4;
        __syncthreads();
        // --- stage A: copy prepacked hi/lo, 128 rows x 64 k
        #pragma unroll
        for (int it = 0; it < 4; ++it) {
            int idx = tid + it * 256;           // 1024 = 128 rows x 8 slots
            int row = idx >> 3, ch = idx & 7;
            size_t off = (size_t)(m0 + row) * 768 + k0 + ch * 8;
            *(uint4*)((char*)Ah + LOFF(row, ch * 16)) = *(const uint4*)(w1h + off);
            *(uint4*)((char*)Al + LOFF(row, ch * 16)) = *(const uint4*)(w1l + off);
        }
        // --- stage B (im2col gather, fp32 -> hi/lo) : 128 n x 64 k
        #pragma unroll
        for (int it = 0; it < 2; ++it) {
            int u = tid + it * 256;             // 512 units of 16 floats
            int r = u >> 5, pw = u & 31;        // r = phl*4 + kyl
            int phl = r >> 2, kyl = r & 3;
            int y = (ph0 + phl) * 16 + ky0 + kyl;
            const float* src = x + (((size_t)b * 3 + ci) * 512 + y) * 512 + pw * 16;
            int n = phl * 32 + pw;
            u16 h[16], l[16];
            split16(src, h, l);
            put16(Bh, n, kyl * 32, h);
            put16(Bl, n, kyl * 32, l);
        }
        __syncthreads();
        #pragma unroll
        for (int kk = 0; kk < 2; ++kk) {
            const int kb = kk * 64 + lk * 16;
            bf16x8 ah[4], al[4], bh[4], bl[4];
            #pragma unroll
            for (int mi = 0; mi < 4; ++mi) {
                int row = wm * 64 + mi * 16 + lr;
                ah[mi] = *(const bf16x8*)((const char*)Ah + LOFF(row, kb));
                al[mi] = *(const bf16x8*)((const char*)Al + LOFF(row, kb));
            }
            #pragma unroll
            for (int ni = 0; ni < 4; ++ni) {
                int row = wn * 64 + ni * 16 + lr;
                bh[ni] = *(const bf16x8*)((const char*)Bh + LOFF(row, kb));
                bl[ni] = *(const bf16x8*)((const char*)Bl + LOFF(row, kb));
            }
            #pragma unroll
            for (int mi = 0; mi < 4; ++mi)
            #pragma unroll
            for (int ni = 0; ni < 4; ++ni) {
                acc[mi][ni] = MFMA(ah[mi], bh[ni], acc[mi][ni]);
                acc[mi][ni] = MFMA(ah[mi], bl[ni], acc[mi][ni]);
                acc[mi][ni] = MFMA(al[mi], bh[ni], acc[mi][ni]);
            }
        }
    }
    // epilogue: split + store to xhi/xlo[b][n][c]
    #pragma unroll
    for (int mi = 0; mi < 4; ++mi)
    #pragma unroll
    for (int ni = 0; ni < 4; ++ni) {
        int c0 = m0 + wm * 64 + mi * 16 + lk * 4;
        int n  = n0 + wn * 64 + ni * 16 + lr;
        ushort4 h4, l4;
        float v0 = acc[mi][ni][0], v1 = acc[mi][ni][1];
        float v2 = acc[mi][ni][2], v3 = acc[mi][ni][3];
        h4.x = f2bf(v0); l4.x = f2bf(v0 - bf2f(h4.x));
        h4.y = f2bf(v1); l4.y = f2bf(v1 - bf2f(h4.y));
        h4.z = f2bf(v2); l4.z = f2bf(v2 - bf2f(h4.z));
        h4.w = f2bf(v3); l4.w = f2bf(v3 - bf2f(h4.w));
        size_t base = ((size_t)b * NP + n) * C_ + c0;
        *(ushort4*)&xhi[base] = h4;
        *(ushort4*)&xlo[base] = l4;
    }
}

// ---------------------------------------------------------------------------
// Kernel P1: q/k projection, split-bf16.  rows 0..63 = q, 64..127 = k.
// tile 128m x 64n, K=512 (8 steps).  grid 512.  W staged by copy (prepacked).
// ---------------------------------------------------------------------------
__global__ __launch_bounds__(256) void projQK(
    const u16* __restrict__ xhi, const u16* __restrict__ xlo,
    const u16* __restrict__ wqkh, const u16* __restrict__ wqkl,
    const float* __restrict__ bq, const float* __restrict__ bk,
    u16* __restrict__ qhi, u16* __restrict__ qlo,
    u16* __restrict__ khi, u16* __restrict__ klo)
{
    __shared__ u16 Wh[128 * 64], Wl[128 * 64], Xh[64 * 64], Xl[64 * 64];
    __shared__ float biasS[128];
    const int tid = threadIdx.x;
    const int b = blockIdx.x >> 4, n0 = (blockIdx.x & 15) * 64;
    const int wid = tid >> 6, lane = tid & 63;
    const int wm = wid >> 1, wn = wid & 1;
    const int lr = lane & 15, lk = lane >> 4;
    if (tid < 128) biasS[tid] = (tid < 64) ? bq[tid] : bk[tid - 64];

    f32x4 acc[4][2];
    #pragma unroll
    for (int i = 0; i < 4; ++i) {
        acc[i][0] = f32x4{0.f, 0.f, 0.f, 0.f};
        acc[i][1] = f32x4{0.f, 0.f, 0.f, 0.f};
    }

    for (int s = 0; s < 8; ++s) {
        const int k0 = s * 64;
        __syncthreads();
        #pragma unroll
        for (int it = 0; it < 4; ++it) {
            int idx = tid + it * 256;           // 128 rows x 8 slots
            int row = idx >> 3, ch = idx & 7;
            size_t off = (size_t)row * C_ + k0 + ch * 8;
            *(uint4*)((char*)Wh + LOFF(row, ch * 16)) = *(const uint4*)(wqkh + off);
            *(uint4*)((char*)Wl + LOFF(row, ch * 16)) = *(const uint4*)(wqkl + off);
        }
        #pragma unroll
        for (int it = 0; it < 4; ++it) {
            int idx = tid + it * 256;
            int sel = idx >> 9, u = idx & 511;
            int row = u >> 3, ch = u & 7;
            const u16* src = (sel ? xlo : xhi) + ((size_t)b * NP + n0 + row) * C_ + k0 + ch * 8;
            uint4 v = *(const uint4*)src;
            *(uint4*)((char*)(sel ? Xl : Xh) + LOFF(row, ch * 16)) = v;
        }
        __syncthreads();
        #pragma unroll
        for (int kk = 0; kk < 2; ++kk) {
            const int kb = kk * 64 + lk * 16;
            bf16x8 ah[4], al[4], bh[2], bl[2];
            #pragma unroll
            for (int mi = 0; mi < 4; ++mi) {
                int row = wm * 64 + mi * 16 + lr;
                ah[mi] = *(const bf16x8*)((const char*)Wh + LOFF(row, kb));
                al[mi] = *(const bf16x8*)((const char*)Wl + LOFF(row, kb));
            }
            #pragma unroll
            for (int ni = 0; ni < 2; ++ni) {
                int row = wn * 32 + ni * 16 + lr;
                bh[ni] = *(const bf16x8*)((const char*)Xh + LOFF(row, kb));
                bl[ni] = *(const bf16x8*)((const char*)Xl + LOFF(row, kb));
            }
            #pragma unroll
            for (int mi = 0; mi < 4; ++mi)
            #pragma unroll
            for (int ni = 0; ni < 2; ++ni) {
                acc[mi][ni] = MFMA(ah[mi], bh[ni], acc[mi][ni]);
                acc[mi][ni] = MFMA(ah[mi], bl[ni], acc[mi][ni]);
                acc[mi][ni] = MFMA(al[mi], bh[ni], acc[mi][ni]);
            }
        }
    }
    #pragma unroll
    for (int mi = 0; mi < 4; ++mi)
    #pragma unroll
    for (int ni = 0; ni < 2; ++ni) {
        int j0 = wm * 64 + mi * 16 + lk * 4;
        int n  = n0 + wn * 32 + ni * 16 + lr;
        float4 bb = *(float4*)&biasS[j0];
        float v0 = acc[mi][ni][0] + bb.x, v1 = acc[mi][ni][1] + bb.y;
        float v2 = acc[mi][ni][2] + bb.z, v3 = acc[mi][ni][3] + bb.w;
        ushort4 h4, l4;
        h4.x = f2bf(v0); l4.x = f2bf(v0 - bf2f(h4.x));
        h4.y = f2bf(v1); l4.y = f2bf(v1 - bf2f(h4.y));
        h4.z = f2bf(v2); l4.z = f2bf(v2 - bf2f(h4.z));
        h4.w = f2bf(v3); l4.w = f2bf(v3 - bf2f(h4.w));
        if (wm == 0) {
            size_t base = ((size_t)b * NP + n) * CQK + j0;
            *(ushort4*)&qhi[base] = h4;
            *(ushort4*)&qlo[base] = l4;
        } else {
            size_t base = ((size_t)b * NP + n) * CQK + (j0 - 64);
            *(ushort4*)&khi[base] = h4;
            *(ushort4*)&klo[base] = l4;
        }
    }
}

// ---------------------------------------------------------------------------
// Kernel P2: v projection, single bf16.  tile 128n x 128cout, K=512 (8 steps).
// grid 1024, XCD-grouped (4 batches per XCD; c-tiles of one n-tile adjacent).
// ---------------------------------------------------------------------------
__global__ __launch_bounds__(256) void projV(
    const u16* __restrict__ xhi, const u16* __restrict__ wvb,
    const float* __restrict__ bv, u16* __restrict__ vws)
{
    __shared__ u16 Xt[128 * 64], Wt[128 * 64];
    __shared__ float biasS[128];
    const int tid = threadIdx.x;
    const int bid = blockIdx.x;
    const int xcd = bid & 7, slot = bid >> 3;
    const int b = xcd * 4 + (slot >> 5);
    const int r = slot & 31;
    const int n0 = (r >> 2) * 128;
    const int c0 = (r & 3) * 128;
    const int wid = tid >> 6, lane = tid & 63;
    const int wm = wid >> 1, wn = wid & 1;
    const int lr = lane & 15, lk = lane >> 4;
    if (tid < 128) biasS[tid] = bv[c0 + tid];

    f32x4 acc[4][4];
    #pragma unroll
    for (int i = 0; i < 4; ++i)
    #pragma unroll
    for (int j = 0; j < 4; ++j) acc[i][j] = f32x4{0.f, 0.f, 0.f, 0.f};

    for (int s = 0; s < 8; ++s) {
        const int k0 = s * 64;
        __syncthreads();
        #pragma unroll
        for (int it = 0; it < 4; ++it) {
            int idx = tid + it * 256;
            int row = idx >> 3, ch = idx & 7;
            const u16* src = xhi + ((size_t)b * NP + n0 + row) * C_ + k0 + ch * 8;
            uint4 v = *(const uint4*)src;
            *(uint4*)((char*)Xt + LOFF(row, ch * 16)) = v;
        }
        #pragma unroll
        for (int it = 0; it < 4; ++it) {
            int idx = tid + it * 256;           // 128 rows x 8 slots
            int row = idx >> 3, ch = idx & 7;
            const u16* src = wvb + (size_t)(c0 + row) * C_ + k0 + ch * 8;
            *(uint4*)((char*)Wt + LOFF(row, ch * 16)) = *(const uint4*)src;
        }
        __syncthreads();
        #pragma unroll
        for (int kk = 0; kk < 2; ++kk) {
            const int kb = kk * 64 + lk * 16;
            bf16x8 a[4], bfr[4];
            #pragma unroll
            for (int mi = 0; mi < 4; ++mi) {
                int row = wm * 64 + mi * 16 + lr;
                a[mi] = *(const bf16x8*)((const char*)Xt + LOFF(row, kb));
            }
            #pragma unroll
            for (int ni = 0; ni < 4; ++ni) {
                int row = wn * 64 + ni * 16 + lr;
                bfr[ni] = *(const bf16x8*)((const char*)Wt + LOFF(row, kb));
            }
            #pragma unroll
            for (int mi = 0; mi < 4; ++mi)
            #pragma unroll
            for (int ni = 0; ni < 4; ++ni)
                acc[mi][ni] = MFMA(a[mi], bfr[ni], acc[mi][ni]);
        }
    }
    #pragma unroll
    for (int mi = 0; mi < 4; ++mi)
    #pragma unroll
    for (int ni = 0; ni < 4; ++ni) {
        int nr0 = n0 + wm * 64 + mi * 16 + lk * 4;
        int c   = c0 + wn * 64 + ni * 16 + lr;
        float bias = biasS[wn * 64 + ni * 16 + lr];
        ushort4 h4;
        h4.x = f2bf(acc[mi][ni][0] + bias);
        h4.y = f2bf(acc[mi][ni][1] + bias);
        h4.z = f2bf(acc[mi][ni][2] + bias);
        h4.w = f2bf(acc[mi][ni][3] + bias);
        *(ushort4*)&vws[((size_t)b * C_ + c) * NP + nr0] = h4;
    }
}

// ---------------------------------------------------------------------------
// Kernel B: E^T[m,n] = k_m . q_n  (split-bf16, swapped operands), clip, exp,
// running Z[n]; writes unnormalized P[b][n][m] bf16 + Z[b][n] fp32.  grid 512.
// ---------------------------------------------------------------------------
__global__ __launch_bounds__(256) void attnE(
    const u16* __restrict__ qhi, const u16* __restrict__ qlo,
    const u16* __restrict__ khi, const u16* __restrict__ klo,
    u16* __restrict__ Pws, float* __restrict__ Zws)
{
    __shared__ u16 Kh[64 * 64], Kl[64 * 64], Qh[64 * 64], Ql[64 * 64];
    __shared__ float zs[64];
    const int tid = threadIdx.x;
    const int b = blockIdx.x >> 4, n0 = (blockIdx.x & 15) * 64;
    const int wid = tid >> 6, lane = tid & 63;
    const int wr = wid >> 1, wn = wid & 1;
    const int lr = lane & 15, lk = lane >> 4;
    if (tid < 64) zs[tid] = 0.f;

    // stage Q (hi+lo) once
    #pragma unroll
    for (int it = 0; it < 4; ++it) {
        int idx = tid + it * 256;
        int sel = idx >> 9, u = idx & 511;
        int row = u >> 3, ch = u & 7;
        const u16* src = (sel ? qlo : qhi) + ((size_t)b * NP + n0 + row) * CQK + ch * 8;
        uint4 v = *(const uint4*)src;
        *(uint4*)((char*)(sel ? Ql : Qh) + LOFF(row, ch * 16)) = v;
    }
    __syncthreads();
    // hoist Q frags to registers
    bf16x8 qh[2][2], ql[2][2];
    #pragma unroll
    for (int ni = 0; ni < 2; ++ni)
    #pragma unroll
    for (int kk = 0; kk < 2; ++kk) {
        int row = wn * 32 + ni * 16 + lr;
        int kb = kk * 64 + lk * 16;
        qh[ni][kk] = *(const bf16x8*)((const char*)Qh + LOFF(row, kb));
        ql[ni][kk] = *(const bf16x8*)((const char*)Ql + LOFF(row, kb));
    }

    float z[2] = {0.f, 0.f};
    for (int ms = 0; ms < 16; ++ms) {
        const int m0 = ms * 64;
        __syncthreads();
        #pragma unroll
        for (int it = 0; it < 4; ++it) {
            int idx = tid + it * 256;
            int sel = idx >> 9, u = idx & 511;
            int row = u >> 3, ch = u & 7;
            const u16* src = (sel ? klo : khi) + ((size_t)b * NP + m0 + row) * CQK + ch * 8;
            uint4 v = *(const uint4*)src;
            *(uint4*)((char*)(sel ? Kl : Kh) + LOFF(row, ch * 16)) = v;
        }
        __syncthreads();
        f32x4 e[2][2];
        #pragma unroll
        for (int i = 0; i < 2; ++i) {
            e[i][0] = f32x4{0.f, 0.f, 0.f, 0.f};
            e[i][1] = f32x4{0.f, 0.f, 0.f, 0.f};
        }
        #pragma unroll
        for (int kk = 0; kk < 2; ++kk) {
            const int kb = kk * 64 + lk * 16;
            bf16x8 ah[2], al[2];
            #pragma unroll
            for (int mi = 0; mi < 2; ++mi) {
                int row = wr * 32 + mi * 16 + lr;
                ah[mi] = *(const bf16x8*)((const char*)Kh + LOFF(row, kb));
                al[mi] = *(const bf16x8*)((const char*)Kl + LOFF(row, kb));
            }
            #pragma unroll
            for (int mi = 0; mi < 2; ++mi)
            #pragma unroll
            for (int ni = 0; ni < 2; ++ni) {
                e[mi][ni] = MFMA(ah[mi], qh[ni][kk], e[mi][ni]);
                e[mi][ni] = MFMA(ah[mi], ql[ni][kk], e[mi][ni]);
                e[mi][ni] = MFMA(al[mi], qh[ni][kk], e[mi][ni]);
            }
        }
        #pragma unroll
        for (int mi = 0; mi < 2; ++mi)
        #pragma unroll
        for (int ni = 0; ni < 2; ++ni) {
            int n  = n0 + wn * 32 + ni * 16 + lr;
            int mg = m0 + wr * 32 + mi * 16 + lk * 4;
            float e0 = __expf(fminf(fmaxf(e[mi][ni][0], -1.f), 1.f));
            float e1 = __expf(fminf(fmaxf(e[mi][ni][1], -1.f), 1.f));
            float e2 = __expf(fminf(fmaxf(e[mi][ni][2], -1.f), 1.f));
            float e3 = __expf(fminf(fmaxf(e[mi][ni][3], -1.f), 1.f));
            z[ni] += e0 + e1 + e2 + e3;
            ushort4 p4;
            p4.x = f2bf(e0); p4.y = f2bf(e1); p4.z = f2bf(e2); p4.w = f2bf(e3);
            *(ushort4*)&Pws[((size_t)b * NP + n) * NP + mg] = p4;
        }
    }
    z[0] += __shfl_xor(z[0], 16); z[0] += __shfl_xor(z[0], 32);
    z[1] += __shfl_xor(z[1], 16); z[1] += __shfl_xor(z[1], 32);
    if (lk == 0) {
        atomicAdd(&zs[wn * 32 + lr], z[0]);
        atomicAdd(&zs[wn * 32 + 16 + lr], z[1]);
    }
    __syncthreads();
    if (tid < 64) Zws[(size_t)b * NP + n0 + tid] = zs[tid];
}

// ---------------------------------------------------------------------------
// Kernel C: out[b][c][n] = (sum_m P[n,m] * v[c,m]) / Z[n]
// tile 128n x 128c, K=1024 (16 steps).  grid 1024, XCD-grouped.
// ---------------------------------------------------------------------------
__global__ __launch_bounds__(256) void pvOut(
    const u16* __restrict__ Pws, const u16* __restrict__ vws,
    const float* __restrict__ Zws, float* __restrict__ out)
{
    __shared__ u16 Pt[128 * 64], Vt[128 * 64];
    __shared__ float zinv[128];
    const int tid = threadIdx.x;
    const int bid = blockIdx.x;
    const int xcd = bid & 7, slot = bid >> 3;
    const int b = xcd * 4 + (slot >> 5);
    const int r = slot & 31;
    const int n0 = (r >> 2) * 128;
    const int c0 = (r & 3) * 128;
    const int wid = tid >> 6, lane = tid & 63;
    const int wm = wid >> 1, wn = wid & 1;
    const int lr = lane & 15, lk = lane >> 4;
    if (tid < 128) zinv[tid] = 1.0f / Zws[(size_t)b * NP + n0 + tid];

    f32x4 acc[4][4];
    #pragma unroll
    for (int i = 0; i < 4; ++i)
    #pragma unroll
    for (int j = 0; j < 4; ++j) acc[i][j] = f32x4{0.f, 0.f, 0.f, 0.f};

    for (int s = 0; s < 16; ++s) {
        const int m0 = s * 64;
        __syncthreads();
        #pragma unroll
        for (int it = 0; it < 4; ++it) {
            int idx = tid + it * 256;
            int row = idx >> 3, ch = idx & 7;
            const u16* src = Pws + ((size_t)b * NP + n0 + row) * NP + m0 + ch * 8;
            uint4 v = *(const uint4*)src;
            *(uint4*)((char*)Pt + LOFF(row, ch * 16)) = v;
        }
        #pragma unroll
        for (int it = 0; it < 4; ++it) {
            int idx = tid + it * 256;
            int row = idx >> 3, ch = idx & 7;
            const u16* src = vws + ((size_t)b * C_ + c0 + row) * NP + m0 + ch * 8;
            uint4 v = *(const uint4*)src;
            *(uint4*)((char*)Vt + LOFF(row, ch * 16)) = v;
        }
        __syncthreads();
        #pragma unroll
        for (int kk = 0; kk < 2; ++kk) {
            const int kb = kk * 64 + lk * 16;
            bf16x8 a[4], bfr[4];
            #pragma unroll
            for (int mi = 0; mi < 4; ++mi) {
                int row = wm * 64 + mi * 16 + lr;
                a[mi] = *(const bf16x8*)((const char*)Pt + LOFF(row, kb));
            }
            #pragma unroll
            for (int ni = 0; ni < 4; ++ni) {
                int row = wn * 64 + ni * 16 + lr;
                bfr[ni] = *(const bf16x8*)((const char*)Vt + LOFF(row, kb));
            }
            #pragma unroll
            for (int mi = 0; mi < 4; ++mi)
            #pragma unroll
            for (int ni = 0; ni < 4; ++ni)
                acc[mi][ni] = MFMA(a[mi], bfr[ni], acc[mi][ni]);
        }
    }
    #pragma unroll
    for (int mi = 0; mi < 4; ++mi)
    #pragma unroll
    for (int ni = 0; ni < 4; ++ni) {
        int nl0 = wm * 64 + mi * 16 + lk * 4;
        int c   = c0 + wn * 64 + ni * 16 + lr;
        float4 zi = *(float4*)&zinv[nl0];
        float4 o;
        o.x = acc[mi][ni][0] * zi.x;
        o.y = acc[mi][ni][1] * zi.y;
        o.z = acc[mi][ni][2] * zi.z;
        o.w = acc[mi][ni][3] * zi.w;
        *(float4*)&out[((size_t)b * C_ + c) * NP + n0 + nl0] = o;
    }
}

// ---------------------------------------------------------------------------
extern "C" void kernel_launch(void* const* d_in, const int* in_sizes, int n_in,
                              void* d_out, int out_size, void* d_ws, size_t ws_size,
                              hipStream_t stream) {
    const float* x  = (const float*)d_in[0];
    const float* w1 = (const float*)d_in[1];
    const float* wq = (const float*)d_in[2];
    const float* bq = (const float*)d_in[3];
    const float* wk = (const float*)d_in[4];
    const float* bk = (const float*)d_in[5];
    const float* wv = (const float*)d_in[6];
    const float* bv = (const float*)d_in[7];
    float* out = (float*)d_out;

    char* ws = (char*)d_ws;
    // workspace layout (bytes), footprint <= 117,571,584:
    u16* xhi = (u16*)(ws + 0);            // 33,554,432
    u16* xlo = (u16*)(ws + 33554432ULL);  // 33,554,432
    u16* Pws = (u16*)(ws + 0);            // 67,108,864 — aliases xhi+xlo (dead by attnE)
    u16* qhi = (u16*)(ws + 67108864ULL);  //  4,194,304
    u16* qlo = (u16*)(ws + 71303168ULL);
    u16* khi = (u16*)(ws + 75497472ULL);
    u16* klo = (u16*)(ws + 79691776ULL);
    u16* vws = (u16*)(ws + 83886080ULL);  // 33,554,432
    float* Zws = (float*)(ws + 117440512ULL); // 131,072  (ends 117,571,584)

    // prepacked weights live in d_out scratch (dead region until pvOut,
    // which overwrites all of d_out in its epilogue):
    char* sc = (char*)d_out;
    u16* w1h  = (u16*)(sc + 0);           // 786,432
    u16* w1l  = (u16*)(sc + 786432);      // 786,432
    u16* wqkh = (u16*)(sc + 1572864);     // 131,072
    u16* wqkl = (u16*)(sc + 1703936);     // 131,072
    u16* wvb  = (u16*)(sc + 1835008);     // 524,288  (ends 2,359,296 << 64 MB)

    prepack<<<352, 256, 0, stream>>>(w1, wq, wk, wv, w1h, w1l, wqkh, wqkl, wvb);
    convA <<<1024, 256, 0, stream>>>(x, w1h, w1l, xhi, xlo);
    projQK<<<512,  256, 0, stream>>>(xhi, xlo, wqkh, wqkl, bq, bk, qhi, qlo, khi, klo);
    projV <<<1024, 256, 0, stream>>>(xhi, wvb, bv, vws);
    attnE <<<512,  256, 0, stream>>>(qhi, qlo, khi, klo, Pws, Zws);
    pvOut <<<1024, 256, 0, stream>>>(Pws, vws, Zws, out);
}

// Round 8
// 369.940 us; speedup vs baseline: 7.3029x; 1.0366x over previous
//
#include <hip/hip_runtime.h>
#include <hip/hip_bf16.h>
#include <cstdint>

typedef unsigned short u16;
typedef unsigned int u32;
typedef __attribute__((ext_vector_type(8))) short bf16x8;
typedef __attribute__((ext_vector_type(4))) float f32x4;

#define B_   32
#define C_   512
#define CQK  64
#define NP   1024

// byte offset into a [rows][64 bf16] LDS tile (row stride 128 B, 16B-slot XOR swizzle)
#define LOFF(row, kb) (((row) << 7) + ((kb) ^ (((row) & 7) << 4)))

__device__ __forceinline__ u16 f2bf(float f) {
    union { __hip_bfloat16 b; u16 u; } cv;
    cv.b = __float2bfloat16(f);
    return cv.u;
}
__device__ __forceinline__ float bf2f(u16 h) {
    return __uint_as_float(((u32)h) << 16);
}

// write 16 bf16 values into tile at (row, kb..kb+31 bytes) honoring swizzle
__device__ __forceinline__ void put16(u16* tile, int row, int kb, const u16* v) {
    char* p = (char*)tile;
    *(ushort4*)(p + LOFF(row, kb))          = *(const ushort4*)(v + 0);
    *(ushort4*)(p + LOFF(row, kb) + 8)      = *(const ushort4*)(v + 4);
    *(ushort4*)(p + LOFF(row, kb + 16))     = *(const ushort4*)(v + 8);
    *(ushort4*)(p + LOFF(row, kb + 16) + 8) = *(const ushort4*)(v + 12);
}

// load 16 fp32, produce hi/lo bf16 splits (hardware cvt)
__device__ __forceinline__ void split16(const float* src, u16* h, u16* l) {
    float f[16];
    *(float4*)&f[0]  = *(const float4*)(src + 0);
    *(float4*)&f[4]  = *(const float4*)(src + 4);
    *(float4*)&f[8]  = *(const float4*)(src + 8);
    *(float4*)&f[12] = *(const float4*)(src + 12);
    #pragma unroll
    for (int i = 0; i < 16; ++i) {
        h[i] = f2bf(f[i]);
        l[i] = f2bf(f[i] - bf2f(h[i]));
    }
}
__device__ __forceinline__ void cvt16(const float* src, u16* h) {
    float f[16];
    *(float4*)&f[0]  = *(const float4*)(src + 0);
    *(float4*)&f[4]  = *(const float4*)(src + 4);
    *(float4*)&f[8]  = *(const float4*)(src + 8);
    *(float4*)&f[12] = *(const float4*)(src + 12);
    #pragma unroll
    for (int i = 0; i < 16; ++i) h[i] = f2bf(f[i]);
}

#define MFMA(a, b, c) __builtin_amdgcn_mfma_f32_16x16x32_bf16((a), (b), (c), 0, 0, 0)

// ---------------------------------------------------------------------------
// Kernel T: transpose w1 [512][768] fp32 -> w1T [768][512] fp32.
// grid (24,16), 256 threads (32x8), 32x32 tiles via padded LDS.
// ---------------------------------------------------------------------------
__global__ __launch_bounds__(256) void transposeW1(
    const float* __restrict__ w1, float* __restrict__ w1T)
{
    __shared__ float t[32][33];
    const int tx = threadIdx.x & 31, ty = threadIdx.x >> 5;
    const int k0 = blockIdx.x * 32, c0 = blockIdx.y * 32;
    #pragma unroll
    for (int j = 0; j < 4; ++j)
        t[ty + j * 8][tx] = w1[(size_t)(c0 + ty + j * 8) * 768 + k0 + tx];
    __syncthreads();
    #pragma unroll
    for (int j = 0; j < 4; ++j)
        w1T[(size_t)(k0 + ty + j * 8) * 512 + c0 + tx] = t[tx][ty + j * 8];
}

// ---------------------------------------------------------------------------
// Kernel W: compose weights.  D[kd][j] = sum_c w1T[kd][c] * W[j][c],
// W rows = concat(wq 64, wk 64, wv 512).  M=768 (6 mt), N=640 (5 nt), K=512.
// nt==0 (q+k rows): split-bf16 3-product, fp32 out -> wqk1h/wqk1l [128][768].
// nt>=1 (v rows): single bf16 -> wv1b [512][768].
// ---------------------------------------------------------------------------
__global__ __launch_bounds__(256) void composeW(
    const float* __restrict__ w1T,
    const float* __restrict__ wq, const float* __restrict__ wk,
    const float* __restrict__ wv,
    u16* __restrict__ wqk1h, u16* __restrict__ wqk1l, u16* __restrict__ wv1b)
{
    __shared__ u16 Ah[128 * 64], Al[128 * 64], Bh[128 * 64], Bl[128 * 64];
    const int tid = threadIdx.x;
    const int m0 = blockIdx.x * 128;      // kd tile
    const int jn0 = blockIdx.y * 128;     // weight-row tile
    const bool qk = (blockIdx.y == 0);
    const int wid = tid >> 6, lane = tid & 63;
    const int wm = wid >> 1, wn = wid & 1;
    const int lr = lane & 15, lk = lane >> 4;

    f32x4 acc[4][4];
    #pragma unroll
    for (int i = 0; i < 4; ++i)
    #pragma unroll
    for (int j = 0; j < 4; ++j) acc[i][j] = f32x4{0.f, 0.f, 0.f, 0.f};

    for (int s = 0; s < 8; ++s) {
        const int k0 = s * 64;
        __syncthreads();
        // stage A (w1T rows = kd), stage B (weight rows = j)
        #pragma unroll
        for (int it = 0; it < 2; ++it) {
            int u = tid + it * 256;       // 512 units
            int row = u >> 2, q = u & 3;
            const float* asrc = w1T + (size_t)(m0 + row) * 512 + k0 + q * 16;
            int j = jn0 + row;
            const float* bsrc = (j < 64 ? wq + (size_t)j * 512
                               : j < 128 ? wk + (size_t)(j - 64) * 512
                                         : wv + (size_t)(j - 128) * 512) + k0 + q * 16;
            if (qk) {
                u16 h[16], l[16];
                split16(asrc, h, l);
                put16(Ah, row, q * 32, h);
                put16(Al, row, q * 32, l);
                split16(bsrc, h, l);
                put16(Bh, row, q * 32, h);
                put16(Bl, row, q * 32, l);
            } else {
                u16 h[16];
                cvt16(asrc, h);
                put16(Ah, row, q * 32, h);
                cvt16(bsrc, h);
                put16(Bh, row, q * 32, h);
            }
        }
        __syncthreads();
        #pragma unroll
        for (int kk = 0; kk < 2; ++kk) {
            const int kb = kk * 64 + lk * 16;
            bf16x8 ah[4], al[4], bh[4], bl[4];
            #pragma unroll
            for (int mi = 0; mi < 4; ++mi) {
                int row = wm * 64 + mi * 16 + lr;
                ah[mi] = *(const bf16x8*)((const char*)Ah + LOFF(row, kb));
                if (qk) al[mi] = *(const bf16x8*)((const char*)Al + LOFF(row, kb));
            }
            #pragma unroll
            for (int ni = 0; ni < 4; ++ni) {
                int row = wn * 64 + ni * 16 + lr;
                bh[ni] = *(const bf16x8*)((const char*)Bh + LOFF(row, kb));
                if (qk) bl[ni] = *(const bf16x8*)((const char*)Bl + LOFF(row, kb));
            }
            #pragma unroll
            for (int mi = 0; mi < 4; ++mi)
            #pragma unroll
            for (int ni = 0; ni < 4; ++ni) {
                acc[mi][ni] = MFMA(ah[mi], bh[ni], acc[mi][ni]);
                if (qk) {
                    acc[mi][ni] = MFMA(ah[mi], bl[ni], acc[mi][ni]);
                    acc[mi][ni] = MFMA(al[mi], bh[ni], acc[mi][ni]);
                }
            }
        }
    }
    #pragma unroll
    for (int mi = 0; mi < 4; ++mi)
    #pragma unroll
    for (int ni = 0; ni < 4; ++ni) {
        int kd0 = m0 + wm * 64 + mi * 16 + lk * 4;
        int j   = jn0 + wn * 64 + ni * 16 + lr;
        float v0 = acc[mi][ni][0], v1 = acc[mi][ni][1];
        float v2 = acc[mi][ni][2], v3 = acc[mi][ni][3];
        if (j < 128) {
            ushort4 h4, l4;
            h4.x = f2bf(v0); l4.x = f2bf(v0 - bf2f(h4.x));
            h4.y = f2bf(v1); l4.y = f2bf(v1 - bf2f(h4.y));
            h4.z = f2bf(v2); l4.z = f2bf(v2 - bf2f(h4.z));
            h4.w = f2bf(v3); l4.w = f2bf(v3 - bf2f(h4.w));
            *(ushort4*)&wqk1h[(size_t)j * 768 + kd0] = h4;
            *(ushort4*)&wqk1l[(size_t)j * 768 + kd0] = l4;
        } else {
            ushort4 h4;
            h4.x = f2bf(v0); h4.y = f2bf(v1); h4.z = f2bf(v2); h4.w = f2bf(v3);
            *(ushort4*)&wv1b[(size_t)(j - 128) * 768 + kd0] = h4;
        }
    }
}

// ---------------------------------------------------------------------------
// Kernel P: fused projection from patches.  K=768 (12 steps), N per batch 1024.
// grid 1280 = 32 b x 8 nt x 5 mt, XCD-grouped (5 mt of one (b,nt) adjacent).
// mt==0: q+k rows [128], 3-product split -> qhi/qlo/khi/klo [b][n][64].
// mt>=1: v rows [(mt-1)*128..], single bf16, swapped operands -> vws [b][c][n].
// ---------------------------------------------------------------------------
__global__ __launch_bounds__(256) void projAll(
    const float* __restrict__ x,
    const u16* __restrict__ wqk1h, const u16* __restrict__ wqk1l,
    const u16* __restrict__ wv1b,
    const float* __restrict__ bq, const float* __restrict__ bk,
    const float* __restrict__ bv,
    u16* __restrict__ qhi, u16* __restrict__ qlo,
    u16* __restrict__ khi, u16* __restrict__ klo,
    u16* __restrict__ vws)
{
    __shared__ u16 lds[4 * 128 * 64];     // 64 KB
    u16* Ah = lds;
    u16* Al = lds + 8192;
    u16* Bh = lds + 16384;
    u16* Bl = lds + 24576;
    __shared__ float biasS[128];

    const int tid = threadIdx.x;
    const int bid = blockIdx.x;
    const int xcd = bid & 7, slot = bid >> 3;      // 160 slots per XCD
    const int b = xcd * 4 + (slot / 40);
    const int r = slot % 40;
    const int nt = r / 5, mt = r % 5;
    const int n0 = nt * 128, ph0 = nt * 4;
    const int wid = tid >> 6, lane = tid & 63;
    const int wm = wid >> 1, wn = wid & 1;
    const int lr = lane & 15, lk = lane >> 4;

    const int cv0 = (mt - 1) * 128;       // v-channel base (mt>=1)
    if (mt == 0) {
        if (tid < 128) biasS[tid] = (tid < 64) ? bq[tid] : bk[tid - 64];
    } else {
        if (tid < 128) biasS[tid] = bv[cv0 + tid];
    }

    f32x4 acc[4][4];
    #pragma unroll
    for (int i = 0; i < 4; ++i)
    #pragma unroll
    for (int j = 0; j < 4; ++j) acc[i][j] = f32x4{0.f, 0.f, 0.f, 0.f};

    for (int s = 0; s < 12; ++s) {
        const int k0 = s * 64;
        const int ci = s >> 2, ky0 = (s & 3) * 4;
        __syncthreads();
        if (mt == 0) {
            // stage A: prepacked wqk1 hi/lo [128][768]
            #pragma unroll
            for (int it = 0; it < 4; ++it) {
                int idx = tid + it * 256;     // 1024 = 128 rows x 8 slots
                int row = idx >> 3, ch = idx & 7;
                size_t off = (size_t)row * 768 + k0 + ch * 8;
                *(uint4*)((char*)Ah + LOFF(row, ch * 16)) = *(const uint4*)(wqk1h + off);
                *(uint4*)((char*)Al + LOFF(row, ch * 16)) = *(const uint4*)(wqk1l + off);
            }
            // stage B: im2col patches, hi/lo split
            #pragma unroll
            for (int it = 0; it < 2; ++it) {
                int u = tid + it * 256;       // 512 units of 16 floats
                int rr = u >> 5, pw = u & 31;
                int phl = rr >> 2, kyl = rr & 3;
                int y = (ph0 + phl) * 16 + ky0 + kyl;
                const float* src = x + (((size_t)b * 3 + ci) * 512 + y) * 512 + pw * 16;
                int n = phl * 32 + pw;
                u16 h[16], l[16];
                split16(src, h, l);
                put16(Bh, n, kyl * 32, h);
                put16(Bl, n, kyl * 32, l);
            }
        } else {
            // stage A: wv1b rows cv0..cv0+127 (into Ah)
            #pragma unroll
            for (int it = 0; it < 4; ++it) {
                int idx = tid + it * 256;
                int row = idx >> 3, ch = idx & 7;
                size_t off = (size_t)(cv0 + row) * 768 + k0 + ch * 8;
                *(uint4*)((char*)Ah + LOFF(row, ch * 16)) = *(const uint4*)(wv1b + off);
            }
            // stage B: im2col patches, hi only
            #pragma unroll
            for (int it = 0; it < 2; ++it) {
                int u = tid + it * 256;
                int rr = u >> 5, pw = u & 31;
                int phl = rr >> 2, kyl = rr & 3;
                int y = (ph0 + phl) * 16 + ky0 + kyl;
                const float* src = x + (((size_t)b * 3 + ci) * 512 + y) * 512 + pw * 16;
                int n = phl * 32 + pw;
                u16 h[16];
                cvt16(src, h);
                put16(Bh, n, kyl * 32, h);
            }
        }
        __syncthreads();
        if (mt == 0) {
            #pragma unroll
            for (int kk = 0; kk < 2; ++kk) {
                const int kb = kk * 64 + lk * 16;
                bf16x8 ah[4], al[4], bh[4], bl[4];
                #pragma unroll
                for (int mi = 0; mi < 4; ++mi) {
                    int row = wm * 64 + mi * 16 + lr;
                    ah[mi] = *(const bf16x8*)((const char*)Ah + LOFF(row, kb));
                    al[mi] = *(const bf16x8*)((const char*)Al + LOFF(row, kb));
                }
                #pragma unroll
                for (int ni = 0; ni < 4; ++ni) {
                    int row = wn * 64 + ni * 16 + lr;
                    bh[ni] = *(const bf16x8*)((const char*)Bh + LOFF(row, kb));
                    bl[ni] = *(const bf16x8*)((const char*)Bl + LOFF(row, kb));
                }
                #pragma unroll
                for (int mi = 0; mi < 4; ++mi)
                #pragma unroll
                for (int ni = 0; ni < 4; ++ni) {
                    acc[mi][ni] = MFMA(ah[mi], bh[ni], acc[mi][ni]);
                    acc[mi][ni] = MFMA(ah[mi], bl[ni], acc[mi][ni]);
                    acc[mi][ni] = MFMA(al[mi], bh[ni], acc[mi][ni]);
                }
            }
        } else {
            #pragma unroll
            for (int kk = 0; kk < 2; ++kk) {
                const int kb = kk * 64 + lk * 16;
                bf16x8 a[4], bfr[4];
                #pragma unroll
                for (int mi = 0; mi < 4; ++mi) {
                    int row = wm * 64 + mi * 16 + lr;
                    a[mi] = *(const bf16x8*)((const char*)Bh + LOFF(row, kb));   // patches
                }
                #pragma unroll
                for (int ni = 0; ni < 4; ++ni) {
                    int row = wn * 64 + ni * 16 + lr;
                    bfr[ni] = *(const bf16x8*)((const char*)Ah + LOFF(row, kb)); // v-weights
                }
                #pragma unroll
                for (int mi = 0; mi < 4; ++mi)
                #pragma unroll
                for (int ni = 0; ni < 4; ++ni)
                    acc[mi][ni] = MFMA(a[mi], bfr[ni], acc[mi][ni]);
            }
        }
    }
    if (mt == 0) {
        #pragma unroll
        for (int mi = 0; mi < 4; ++mi)
        #pragma unroll
        for (int ni = 0; ni < 4; ++ni) {
            int j0 = wm * 64 + mi * 16 + lk * 4;
            int n  = n0 + wn * 64 + ni * 16 + lr;
            float4 bb = *(float4*)&biasS[j0];
            float v0 = acc[mi][ni][0] + bb.x, v1 = acc[mi][ni][1] + bb.y;
            float v2 = acc[mi][ni][2] + bb.z, v3 = acc[mi][ni][3] + bb.w;
            ushort4 h4, l4;
            h4.x = f2bf(v0); l4.x = f2bf(v0 - bf2f(h4.x));
            h4.y = f2bf(v1); l4.y = f2bf(v1 - bf2f(h4.y));
            h4.z = f2bf(v2); l4.z = f2bf(v2 - bf2f(h4.z));
            h4.w = f2bf(v3); l4.w = f2bf(v3 - bf2f(h4.w));
            if (j0 < 64) {
                size_t base = ((size_t)b * NP + n) * CQK + j0;
                *(ushort4*)&qhi[base] = h4;
                *(ushort4*)&qlo[base] = l4;
            } else {
                size_t base = ((size_t)b * NP + n) * CQK + (j0 - 64);
                *(ushort4*)&khi[base] = h4;
                *(ushort4*)&klo[base] = l4;
            }
        }
    } else {
        #pragma unroll
        for (int mi = 0; mi < 4; ++mi)
        #pragma unroll
        for (int ni = 0; ni < 4; ++ni) {
            int nr0 = n0 + wm * 64 + mi * 16 + lk * 4;
            int c   = cv0 + wn * 64 + ni * 16 + lr;
            float bias = biasS[wn * 64 + ni * 16 + lr];
            ushort4 h4;
            h4.x = f2bf(acc[mi][ni][0] + bias);
            h4.y = f2bf(acc[mi][ni][1] + bias);
            h4.z = f2bf(acc[mi][ni][2] + bias);
            h4.w = f2bf(acc[mi][ni][3] + bias);
            *(ushort4*)&vws[((size_t)b * C_ + c) * NP + nr0] = h4;
        }
    }
}

// ---------------------------------------------------------------------------
// Kernel B: E^T[m,n] = k_m . q_n  (split-bf16, swapped operands), clip, exp,
// running Z[n]; writes unnormalized P[b][n][m] bf16 + Z[b][n] fp32.  grid 512.
// ---------------------------------------------------------------------------
__global__ __launch_bounds__(256) void attnE(
    const u16* __restrict__ qhi, const u16* __restrict__ qlo,
    const u16* __restrict__ khi, const u16* __restrict__ klo,
    u16* __restrict__ Pws, float* __restrict__ Zws)
{
    __shared__ u16 Kh[64 * 64], Kl[64 * 64], Qh[64 * 64], Ql[64 * 64];
    __shared__ float zs[64];
    const int tid = threadIdx.x;
    const int b = blockIdx.x >> 4, n0 = (blockIdx.x & 15) * 64;
    const int wid = tid >> 6, lane = tid & 63;
    const int wr = wid >> 1, wn = wid & 1;
    const int lr = lane & 15, lk = lane >> 4;
    if (tid < 64) zs[tid] = 0.f;

    // stage Q (hi+lo) once
    #pragma unroll
    for (int it = 0; it < 4; ++it) {
        int idx = tid + it * 256;
        int sel = idx >> 9, u = idx & 511;
        int row = u >> 3, ch = u & 7;
        const u16* src = (sel ? qlo : qhi) + ((size_t)b * NP + n0 + row) * CQK + ch * 8;
        uint4 v = *(const uint4*)src;
        *(uint4*)((char*)(sel ? Ql : Qh) + LOFF(row, ch * 16)) = v;
    }
    __syncthreads();
    // hoist Q frags to registers
    bf16x8 qh[2][2], ql[2][2];
    #pragma unroll
    for (int ni = 0; ni < 2; ++ni)
    #pragma unroll
    for (int kk = 0; kk < 2; ++kk) {
        int row = wn * 32 + ni * 16 + lr;
        int kb = kk * 64 + lk * 16;
        qh[ni][kk] = *(const bf16x8*)((const char*)Qh + LOFF(row, kb));
        ql[ni][kk] = *(const bf16x8*)((const char*)Ql + LOFF(row, kb));
    }

    float z[2] = {0.f, 0.f};
    for (int ms = 0; ms < 16; ++ms) {
        const int m0 = ms * 64;
        __syncthreads();
        #pragma unroll
        for (int it = 0; it < 4; ++it) {
            int idx = tid + it * 256;
            int sel = idx >> 9, u = idx & 511;
            int row = u >> 3, ch = u & 7;
            const u16* src = (sel ? klo : khi) + ((size_t)b * NP + m0 + row) * CQK + ch * 8;
            uint4 v = *(const uint4*)src;
            *(uint4*)((char*)(sel ? Kl : Kh) + LOFF(row, ch * 16)) = v;
        }
        __syncthreads();
        f32x4 e[2][2];
        #pragma unroll
        for (int i = 0; i < 2; ++i) {
            e[i][0] = f32x4{0.f, 0.f, 0.f, 0.f};
            e[i][1] = f32x4{0.f, 0.f, 0.f, 0.f};
        }
        #pragma unroll
        for (int kk = 0; kk < 2; ++kk) {
            const int kb = kk * 64 + lk * 16;
            bf16x8 ah[2], al[2];
            #pragma unroll
            for (int mi = 0; mi < 2; ++mi) {
                int row = wr * 32 + mi * 16 + lr;
                ah[mi] = *(const bf16x8*)((const char*)Kh + LOFF(row, kb));
                al[mi] = *(const bf16x8*)((const char*)Kl + LOFF(row, kb));
            }
            #pragma unroll
            for (int mi = 0; mi < 2; ++mi)
            #pragma unroll
            for (int ni = 0; ni < 2; ++ni) {
                e[mi][ni] = MFMA(ah[mi], qh[ni][kk], e[mi][ni]);
                e[mi][ni] = MFMA(ah[mi], ql[ni][kk], e[mi][ni]);
                e[mi][ni] = MFMA(al[mi], qh[ni][kk], e[mi][ni]);
            }
        }
        #pragma unroll
        for (int mi = 0; mi < 2; ++mi)
        #pragma unroll
        for (int ni = 0; ni < 2; ++ni) {
            int n  = n0 + wn * 32 + ni * 16 + lr;
            int mg = m0 + wr * 32 + mi * 16 + lk * 4;
            float e0 = __expf(fminf(fmaxf(e[mi][ni][0], -1.f), 1.f));
            float e1 = __expf(fminf(fmaxf(e[mi][ni][1], -1.f), 1.f));
            float e2 = __expf(fminf(fmaxf(e[mi][ni][2], -1.f), 1.f));
            float e3 = __expf(fminf(fmaxf(e[mi][ni][3], -1.f), 1.f));
            z[ni] += e0 + e1 + e2 + e3;
            ushort4 p4;
            p4.x = f2bf(e0); p4.y = f2bf(e1); p4.z = f2bf(e2); p4.w = f2bf(e3);
            *(ushort4*)&Pws[((size_t)b * NP + n) * NP + mg] = p4;
        }
    }
    z[0] += __shfl_xor(z[0], 16); z[0] += __shfl_xor(z[0], 32);
    z[1] += __shfl_xor(z[1], 16); z[1] += __shfl_xor(z[1], 32);
    if (lk == 0) {
        atomicAdd(&zs[wn * 32 + lr], z[0]);
        atomicAdd(&zs[wn * 32 + 16 + lr], z[1]);
    }
    __syncthreads();
    if (tid < 64) Zws[(size_t)b * NP + n0 + tid] = zs[tid];
}

// ---------------------------------------------------------------------------
// Kernel C: out[b][c][n] = (sum_m P[n,m] * v[c,m]) / Z[n]
// tile 128n x 128c, K=1024 (16 steps).  grid 1024, XCD-grouped.
// ---------------------------------------------------------------------------
__global__ __launch_bounds__(256) void pvOut(
    const u16* __restrict__ Pws, const u16* __restrict__ vws,
    const float* __restrict__ Zws, float* __restrict__ out)
{
    __shared__ u16 Pt[128 * 64], Vt[128 * 64];
    __shared__ float zinv[128];
    const int tid = threadIdx.x;
    const int bid = blockIdx.x;
    const int xcd = bid & 7, slot = bid >> 3;
    const int b = xcd * 4 + (slot >> 5);
    const int r = slot & 31;
    const int n0 = (r >> 2) * 128;
    const int c0 = (r & 3) * 128;
    const int wid = tid >> 6, lane = tid & 63;
    const int wm = wid >> 1, wn = wid & 1;
    const int lr = lane & 15, lk = lane >> 4;
    if (tid < 128) zinv[tid] = 1.0f / Zws[(size_t)b * NP + n0 + tid];

    f32x4 acc[4][4];
    #pragma unroll
    for (int i = 0; i < 4; ++i)
    #pragma unroll
    for (int j = 0; j < 4; ++j) acc[i][j] = f32x4{0.f, 0.f, 0.f, 0.f};

    for (int s = 0; s < 16; ++s) {
        const int m0 = s * 64;
        __syncthreads();
        #pragma unroll
        for (int it = 0; it < 4; ++it) {
            int idx = tid + it * 256;
            int row = idx >> 3, ch = idx & 7;
            const u16* src = Pws + ((size_t)b * NP + n0 + row) * NP + m0 + ch * 8;
            uint4 v = *(const uint4*)src;
            *(uint4*)((char*)Pt + LOFF(row, ch * 16)) = v;
        }
        #pragma unroll
        for (int it = 0; it < 4; ++it) {
            int idx = tid + it * 256;
            int row = idx >> 3, ch = idx & 7;
            const u16* src = vws + ((size_t)b * C_ + c0 + row) * NP + m0 + ch * 8;
            uint4 v = *(const uint4*)src;
            *(uint4*)((char*)Vt + LOFF(row, ch * 16)) = v;
        }
        __syncthreads();
        #pragma unroll
        for (int kk = 0; kk < 2; ++kk) {
            const int kb = kk * 64 + lk * 16;
            bf16x8 a[4], bfr[4];
            #pragma unroll
            for (int mi = 0; mi < 4; ++mi) {
                int row = wm * 64 + mi * 16 + lr;
                a[mi] = *(const bf16x8*)((const char*)Pt + LOFF(row, kb));
            }
            #pragma unroll
            for (int ni = 0; ni < 4; ++ni) {
                int row = wn * 64 + ni * 16 + lr;
                bfr[ni] = *(const bf16x8*)((const char*)Vt + LOFF(row, kb));
            }
            #pragma unroll
            for (int mi = 0; mi < 4; ++mi)
            #pragma unroll
            for (int ni = 0; ni < 4; ++ni)
                acc[mi][ni] = MFMA(a[mi], bfr[ni], acc[mi][ni]);
        }
    }
    #pragma unroll
    for (int mi = 0; mi < 4; ++mi)
    #pragma unroll
    for (int ni = 0; ni < 4; ++ni) {
        int nl0 = wm * 64 + mi * 16 + lk * 4;
        int c   = c0 + wn * 64 + ni * 16 + lr;
        float4 zi = *(float4*)&zinv[nl0];
        float4 o;
        o.x = acc[mi][ni][0] * zi.x;
        o.y = acc[mi][ni][1] * zi.y;
        o.z = acc[mi][ni][2] * zi.z;
        o.w = acc[mi][ni][3] * zi.w;
        *(float4*)&out[((size_t)b * C_ + c) * NP + n0 + nl0] = o;
    }
}

// ---------------------------------------------------------------------------
extern "C" void kernel_launch(void* const* d_in, const int* in_sizes, int n_in,
                              void* d_out, int out_size, void* d_ws, size_t ws_size,
                              hipStream_t stream) {
    const float* x  = (const float*)d_in[0];
    const float* w1 = (const float*)d_in[1];
    const float* wq = (const float*)d_in[2];
    const float* bq = (const float*)d_in[3];
    const float* wk = (const float*)d_in[4];
    const float* bk = (const float*)d_in[5];
    const float* wv = (const float*)d_in[6];
    const float* bv = (const float*)d_in[7];
    float* out = (float*)d_out;

    char* ws = (char*)d_ws;
    // workspace layout (bytes), footprint <= 117,571,584 (proven):
    u16* Pws = (u16*)(ws + 0);            // 67,108,864
    u16* qhi = (u16*)(ws + 67108864ULL);  //  4,194,304
    u16* qlo = (u16*)(ws + 71303168ULL);
    u16* khi = (u16*)(ws + 75497472ULL);
    u16* klo = (u16*)(ws + 79691776ULL);
    u16* vws = (u16*)(ws + 83886080ULL);  // 33,554,432
    float* Zws = (float*)(ws + 117440512ULL); // 131,072  (ends 117,571,584)

    // composed weights live in d_out scratch (dead region until pvOut,
    // which overwrites all of d_out in its epilogue):
    char* sc = (char*)d_out;
    float* w1T  = (float*)(sc + 0);        // 1,572,864  (768x512 fp32)
    u16* wqk1h  = (u16*)(sc + 1572864);    //   196,608  (128x768 bf16)
    u16* wqk1l  = (u16*)(sc + 1769472);    //   196,608
    u16* wv1b   = (u16*)(sc + 1966080);    //   786,432  (512x768 bf16) ends 2,752,512

    transposeW1<<<dim3(24, 16), 256, 0, stream>>>(w1, w1T);
    composeW<<<dim3(6, 5), 256, 0, stream>>>(w1T, wq, wk, wv, wqk1h, wqk1l, wv1b);
    projAll<<<1280, 256, 0, stream>>>(x, wqk1h, wqk1l, wv1b, bq, bk, bv,
                                      qhi, qlo, khi, klo, vws);
    attnE <<<512,  256, 0, stream>>>(qhi, qlo, khi, klo, Pws, Zws);
    pvOut <<<1024, 256, 0, stream>>>(Pws, vws, Zws, out);
}